// Round 5
// baseline (582.258 us; speedup 1.0000x reference)
//
#include <hip/hip_runtime.h>
#include <float.h>

#define B_   8
#define C_   64
#define N_   4096
#define OUT_ 128
#define KNN  9
#define CAP  128         // candidate buffer capacity per row (refine handles <=128)
#define TAU_A 2.3f       // threshold: tau = TAU_A*sigma_n - 64

typedef __attribute__((ext_vector_type(8))) short short8;
typedef __attribute__((ext_vector_type(4))) float f32x4;

__device__ inline unsigned short f2bf(float f) {
    unsigned u = __float_as_uint(f);
    unsigned r = (u + 0x7fffu + ((u >> 16) & 1u)) >> 16;
    return (unsigned short)r;
}
__device__ inline float bf2f(unsigned short s) {
    return __uint_as_float(((unsigned)s) << 16);
}

// ---------------------------------------------------------------------------
// ws layout (bytes):
//   xT:    [B][N][C] float     @ 0          (8388608)
//   xfrag: hi/lo bf16 chunks   @ 8388608    (8388608)  } idx9 aliases xfrag:
//   idx9:  [B*N][9]  int       @ 8388608    (1179648)  } xfrag dead by refine
//   x2:    [B][N]    float     @ 16777216   (131072)
//   WT:    [2C][OUT] float     @ 16908288   (65536)
//   cand:  [B*N][128] ushort   @ 16973824   (8388608)
//   cnt:   [B*N]     int       @ 25362432   (131072)   total ~24.3 MB
// ---------------------------------------------------------------------------

__global__ void k_wt(const float* __restrict__ W, float* __restrict__ WT) {
    int e = blockIdx.x * 256 + threadIdx.x;
    int o = e >> 7, c = e & 127;
    WT[(size_t)c * OUT_ + o] = W[e];
}

__global__ void k_transpose(const float* __restrict__ x, float* __restrict__ xT,
                            float* __restrict__ x2) {
    __shared__ float t[C_][65];
    int b  = blockIdx.x >> 6;
    int n0 = (blockIdx.x & 63) * 64;
    int tid = threadIdx.x;
    for (int i = 0; i < 16; ++i) {
        int e = i * 256 + tid;
        int c = e >> 6, nn = e & 63;
        t[c][nn] = x[((size_t)b * C_ + c) * N_ + n0 + nn];
    }
    __syncthreads();
    for (int i = 0; i < 16; ++i) {
        int e = i * 256 + tid;
        int nn = e >> 6, c = e & 63;
        xT[((size_t)b * N_ + n0 + nn) * C_ + c] = t[c][nn];
    }
    if (tid < 64) {
        float s = 0.f;
        for (int c = 0; c < C_; ++c) { float v = t[c][tid]; s += v * v; }
        x2[(size_t)b * N_ + n0 + tid] = s;
    }
}

// build bf16 hi/lo fragment chunks from xT (mfma_f32_16x16x32_bf16 load order)
__global__ void k_prep(const float* __restrict__ xT, unsigned short* __restrict__ xfrag) {
    int tid = threadIdx.x;
    int t = blockIdx.x * 2 + (tid >> 7);        // global m-tile 0..2047
    int h = (tid >> 6) & 1;
    int L = tid & 63;
    int b = t >> 8, tb = t & 255;
    int m = tb * 16 + (L & 15);
    int ks = h * 32 + ((L >> 4) * 8);
    const float* src = xT + ((size_t)b * N_ + m) * C_ + ks;
    float4 v0 = *(const float4*)(src);
    float4 v1 = *(const float4*)(src + 4);
    float vs[8] = {v0.x, v0.y, v0.z, v0.w, v1.x, v1.y, v1.z, v1.w};
    short8 hi, lo;
#pragma unroll
    for (int j = 0; j < 8; ++j) {
        unsigned short hb = f2bf(vs[j]);
        float hf = bf2f(hb);
        unsigned short lb = f2bf(vs[j] - hf);
        hi[j] = (short)hb; lo[j] = (short)lb;
    }
    size_t cb = ((size_t)t * 4 + h * 2) * 512;   // ushort units (chunk=512 ushort)
    *(short8*)(xfrag + cb + L * 8)       = hi;
    *(short8*)(xfrag + cb + 512 + L * 8) = lo;
}

#define APPEND(KEY, TAU, LN, MIDX)                                      \
    if ((KEY) > (TAU)) {                                                \
        int sl = atomicAdd(&cnt_s[LN], 1);                              \
        if (sl < CAP) buf_s[LN][sl] = (unsigned short)(MIDX);           \
    }

// MFMA scan + threshold compaction. block = (b = blockIdx&7, ng = blockIdx>>3).
// 64 n's per block (4 B-tile pairs); wave w scans m in [w*1024,(w+1)*1024).
__global__ __launch_bounds__(256, 2) void k_topk_mf(const unsigned short* __restrict__ xfrag,
                                                    const float* __restrict__ x2,
                                                    unsigned short* __restrict__ candg,
                                                    int* __restrict__ cntg) {
    __shared__ int cnt_s[64];
    __shared__ unsigned short buf_s[64][CAP];
    int b    = blockIdx.x & 7;
    int ng   = blockIdx.x >> 3;                  // 0..63
    int wave = threadIdx.x >> 6, lane = threadIdx.x & 63;
    if (threadIdx.x < 64) cnt_s[threadIdx.x] = 0;

    const short8* fr = (const short8*)xfrag;     // 16B units; chunk = 64 short8

    short8 Bh[4][2], Bl[4][2];
#pragma unroll
    for (int q = 0; q < 4; ++q)
#pragma unroll
        for (int h = 0; h < 2; ++h) {
            int ch = ((b * 256 + ng * 4 + q) * 4 + h * 2);
            Bh[q][h] = fr[(size_t)ch * 64 + lane];
            Bl[q][h] = fr[(size_t)(ch + 1) * 64 + lane];
        }

    float tau[4];
#pragma unroll
    for (int q = 0; q < 4; ++q) {
        float x2n = x2[b * N_ + ng * 64 + q * 16 + (lane & 15)];
        tau[q] = TAU_A * sqrtf(fmaf(4.f, x2n, 128.f)) - 64.f;
    }

    int mt0 = wave * 64;
    size_t cb = (size_t)(b * 256 + mt0) * 4;
    short8 Ah0 = fr[cb * 64 + lane],       Al0 = fr[(cb + 1) * 64 + lane];
    short8 Ah1 = fr[(cb + 2) * 64 + lane], Al1 = fr[(cb + 3) * 64 + lane];
    f32x4 x2v = *(const f32x4*)(x2 + b * N_ + mt0 * 16 + (lane >> 4) * 4);

    __syncthreads();   // cnt_s zeroed

    for (int i = 0; i < 64; ++i) {
        int inext = (i + 1 < 64) ? i + 1 : i;
        size_t cn = (size_t)(b * 256 + mt0 + inext) * 4;
        short8 nAh0 = fr[cn * 64 + lane],       nAl0 = fr[(cn + 1) * 64 + lane];
        short8 nAh1 = fr[(cn + 2) * 64 + lane], nAl1 = fr[(cn + 3) * 64 + lane];
        f32x4 nx2 = *(const f32x4*)(x2 + b * N_ + (mt0 + inext) * 16 + (lane >> 4) * 4);

        int mbase = (mt0 + i) * 16 + (lane >> 4) * 4;

#pragma unroll
        for (int q = 0; q < 4; ++q) {
            f32x4 acc = {0.f, 0.f, 0.f, 0.f};
            acc = __builtin_amdgcn_mfma_f32_16x16x32_bf16(Ah0, Bh[q][0], acc, 0, 0, 0);
            acc = __builtin_amdgcn_mfma_f32_16x16x32_bf16(Ah1, Bh[q][1], acc, 0, 0, 0);
            acc = __builtin_amdgcn_mfma_f32_16x16x32_bf16(Al0, Bh[q][0], acc, 0, 0, 0);
            acc = __builtin_amdgcn_mfma_f32_16x16x32_bf16(Al1, Bh[q][1], acc, 0, 0, 0);
            acc = __builtin_amdgcn_mfma_f32_16x16x32_bf16(Ah0, Bl[q][0], acc, 0, 0, 0);
            acc = __builtin_amdgcn_mfma_f32_16x16x32_bf16(Ah1, Bl[q][1], acc, 0, 0, 0);
            float k0 = fmaf(2.f, acc[0], -x2v[0]);
            float k1 = fmaf(2.f, acc[1], -x2v[1]);
            float k2 = fmaf(2.f, acc[2], -x2v[2]);
            float k3 = fmaf(2.f, acc[3], -x2v[3]);
            int ln = q * 16 + (lane & 15);
            APPEND(k0, tau[q], ln, mbase + 0)
            APPEND(k1, tau[q], ln, mbase + 1)
            APPEND(k2, tau[q], ln, mbase + 2)
            APPEND(k3, tau[q], ln, mbase + 3)
        }
        Ah0 = nAh0; Al0 = nAl0; Ah1 = nAh1; Al1 = nAl1; x2v = nx2;
    }

    __syncthreads();
    int r = threadIdx.x >> 2, sub = threadIdx.x & 3;
    int c = cnt_s[r];
    size_t grow = (size_t)b * N_ + ng * 64 + r;
    if (sub == 0) cntg[grow] = c;
    int cc = min(c, CAP);
    for (int s = sub; s < cc; s += 4) candg[grow * CAP + s] = buf_s[r][s];
}

// lane-per-candidate exact fp64 re-rank -> true top-9. Wave per row, 2 cand/lane.
__global__ void k_refine(const float* __restrict__ xT, const unsigned short* __restrict__ candg,
                         const int* __restrict__ cntg, int* __restrict__ idx9) {
    int wave = threadIdx.x >> 6, lane = threadIdx.x & 63;
    int row = blockIdx.x * 4 + wave;
    int cnt = cntg[row];
    if (cnt < KNN || cnt > CAP) return;   // fallback kernel handles
    int b = row >> 12;
    const float* xi = xT + (size_t)row * C_;                 // broadcast loads

    int j0 = min(lane, cnt - 1);
    int m0 = candg[(size_t)row * CAP + j0];
    const float* xa = xT + (((size_t)b << 12) + m0) * C_;
    double d0 = 0.0, s20 = 0.0;
#pragma unroll
    for (int c4 = 0; c4 < 16; ++c4) {
        float4 a = *(const float4*)(xi + c4 * 4);
        float4 v = *(const float4*)(xa + c4 * 4);
        d0 = fma((double)a.x, (double)v.x, d0);  s20 = fma((double)v.x, (double)v.x, s20);
        d0 = fma((double)a.y, (double)v.y, d0);  s20 = fma((double)v.y, (double)v.y, s20);
        d0 = fma((double)a.z, (double)v.z, d0);  s20 = fma((double)v.z, (double)v.z, s20);
        d0 = fma((double)a.w, (double)v.w, d0);  s20 = fma((double)v.w, (double)v.w, s20);
    }
    double k0 = 2.0 * d0 - s20; int i0 = m0;
    if (lane >= cnt) { k0 = -1e300; i0 = 0x7fffffff; }

    double k1 = -1e300; int i1 = 0x7fffffff;
    if (cnt > 64) {                              // wave-uniform branch
        int j1 = min(lane + 64, cnt - 1);
        int m1 = candg[(size_t)row * CAP + j1];
        const float* xb = xT + (((size_t)b << 12) + m1) * C_;
        double d1 = 0.0, s21 = 0.0;
#pragma unroll
        for (int c4 = 0; c4 < 16; ++c4) {
            float4 a = *(const float4*)(xi + c4 * 4);
            float4 v = *(const float4*)(xb + c4 * 4);
            d1 = fma((double)a.x, (double)v.x, d1);  s21 = fma((double)v.x, (double)v.x, s21);
            d1 = fma((double)a.y, (double)v.y, d1);  s21 = fma((double)v.y, (double)v.y, s21);
            d1 = fma((double)a.z, (double)v.z, d1);  s21 = fma((double)v.z, (double)v.z, s21);
            d1 = fma((double)a.w, (double)v.w, d1);  s21 = fma((double)v.w, (double)v.w, s21);
        }
        if (lane + 64 < cnt) { k1 = 2.0 * d1 - s21; i1 = m1; }
    }

    for (int r = 0; r < KNN; ++r) {
        bool f = (k0 > k1) || (k0 == k1 && i0 < i1);
        double k = f ? k0 : k1; int ix = f ? i0 : i1;
#pragma unroll
        for (int o = 32; o; o >>= 1) {
            double ok = __shfl_xor(k, o); int oi = __shfl_xor(ix, o);
            bool take = (ok > k) || (ok == k && oi < ix);
            k = take ? ok : k; ix = take ? oi : ix;
        }
        if (lane == 0) idx9[(size_t)row * KNN + r] = ix;
        if (i0 == ix) { k0 = -1e300; i0 = 0x7fffffff; }   // indices unique per row
        if (i1 == ix) { k1 = -1e300; i1 = 0x7fffffff; }
    }
}

// exact fp64 full scan for rows where the threshold buffer failed (near-never)
__global__ void k_fallback(const float* __restrict__ xT, const int* __restrict__ cntg,
                           int* __restrict__ idx9) {
    int wave = threadIdx.x >> 6, lane = threadIdx.x & 63;
    int w = blockIdx.x * 4 + wave;
    for (int rr = 0; rr < 16; ++rr) {
        int row = w * 16 + rr;
        int cnt = cntg[row];
        if (cnt >= KNN && cnt <= CAP) continue;
        int b = row >> 12;
        const float* xi = xT + (size_t)row * C_;
        double sk[9]; int si[9];
#pragma unroll
        for (int j = 0; j < 9; ++j) { sk[j] = -1e300; si[j] = 0x7fffffff; }
        for (int mb = 0; mb < N_; mb += 64) {
            int m = mb + lane;
            const float* xm = xT + (((size_t)b << 12) + m) * C_;
            double d = 0.0, s2 = 0.0;
            for (int c = 0; c < C_; ++c) {
                double v = xm[c];
                d += (double)xi[c] * v; s2 += v * v;
            }
            double key = 2.0 * d - s2;
            if (key > sk[0] || (key == sk[0] && m < si[0])) {
                sk[0] = key; si[0] = m;
#pragma unroll
                for (int j = 0; j < 8; ++j) {
                    bool sw = (sk[j] > sk[j + 1]) || (sk[j] == sk[j + 1] && si[j] < si[j + 1]);
                    double tk = sk[j]; int ti = si[j];
                    sk[j]     = sw ? sk[j + 1] : sk[j];
                    si[j]     = sw ? si[j + 1] : si[j];
                    sk[j + 1] = sw ? tk : sk[j + 1];
                    si[j + 1] = sw ? ti : si[j + 1];
                }
            }
        }
        for (int r = 0; r < KNN; ++r) {
            double k = sk[8]; int ix = si[8];
#pragma unroll
            for (int o = 32; o; o >>= 1) {
                double ok = __shfl_xor(k, o); int oi = __shfl_xor(ix, o);
                bool take = (ok > k) || (ok == k && oi < ix);
                k = take ? ok : k; ix = take ? oi : ix;
            }
            if (lane == 0) idx9[(size_t)row * KNN + r] = ix;
            if (si[8] == ix) {
#pragma unroll
                for (int j = 8; j > 0; --j) { sk[j] = sk[j - 1]; si[j] = si[j - 1]; }
                sk[0] = -1e300; si[0] = 0x7fffffff;
            }
        }
    }
}

// fused: gather-max (x_j - x_i) into LDS h-tile, then 1x1 conv + bias + ReLU
__global__ void k_gemm(const float* __restrict__ xT, const int* __restrict__ idx9,
                       const float* __restrict__ WT, const float* __restrict__ bias,
                       float* __restrict__ out) {
    __shared__ float h[64][129];
    int b  = blockIdx.x >> 6;
    int n0 = (blockIdx.x & 63) * 64;
    int wave = threadIdx.x >> 6, lane = threadIdx.x & 63;
    for (int r = 0; r < 16; ++r) {
        int nn = wave * 16 + r;
        size_t row = (size_t)b * N_ + n0 + nn;
        const int* id = idx9 + row * KNN;
        float m = -FLT_MAX;
#pragma unroll
        for (int k = 0; k < KNN; ++k) {
            int j = id[k];
            m = fmaxf(m, xT[(((size_t)b << 12) + j) * C_ + lane]);
        }
        float xic = xT[row * C_ + lane];
        h[nn][lane]      = xic;
        h[nn][64 + lane] = m - xic;
    }
    __syncthreads();
    int o0 = wave * 32;
    float acc[32];
#pragma unroll
    for (int j = 0; j < 32; ++j) acc[j] = 0.f;
    for (int c = 0; c < 2 * C_; ++c) {
        float hv = h[lane][c];
        const float4* wrow = (const float4*)(WT + (size_t)c * OUT_ + o0);
#pragma unroll
        for (int j4 = 0; j4 < 8; ++j4) {
            float4 w = wrow[j4];
            acc[j4 * 4 + 0] += w.x * hv;
            acc[j4 * 4 + 1] += w.y * hv;
            acc[j4 * 4 + 2] += w.z * hv;
            acc[j4 * 4 + 3] += w.w * hv;
        }
    }
#pragma unroll
    for (int j = 0; j < 32; ++j) {
        float v = acc[j] + bias[o0 + j];
        v = fmaxf(v, 0.f);
        out[((size_t)b * OUT_ + o0 + j) * N_ + n0 + lane] = v;
    }
}

extern "C" void kernel_launch(void* const* d_in, const int* in_sizes, int n_in,
                              void* d_out, int out_size, void* d_ws, size_t ws_size,
                              hipStream_t stream) {
    const float* x    = (const float*)d_in[0];
    const float* W    = (const float*)d_in[1];
    const float* bias = (const float*)d_in[2];
    float* out = (float*)d_out;
    char* ws = (char*)d_ws;

    float*          xT    = (float*)(ws);
    unsigned short* xfrag = (unsigned short*)(ws + 8388608);
    int*            idx9  = (int*)(ws + 8388608);         // aliases xfrag (dead by refine)
    float*          x2    = (float*)(ws + 16777216);
    float*          WT    = (float*)(ws + 16908288);
    unsigned short* cand  = (unsigned short*)(ws + 16973824);
    int*            cnt   = (int*)(ws + 25362432);

    k_wt       <<<dim3(64),   dim3(256), 0, stream>>>(W, WT);
    k_transpose<<<dim3(512),  dim3(256), 0, stream>>>(x, xT, x2);
    k_prep     <<<dim3(1024), dim3(256), 0, stream>>>(xT, xfrag);
    k_topk_mf  <<<dim3(512),  dim3(256), 0, stream>>>(xfrag, x2, cand, cnt);
    k_refine   <<<dim3(8192), dim3(256), 0, stream>>>(xT, cand, cnt, idx9);
    k_fallback <<<dim3(512),  dim3(256), 0, stream>>>(xT, cnt, idx9);
    k_gemm     <<<dim3(512),  dim3(256), 0, stream>>>(xT, idx9, WT, bias, out);
}

// Round 6
// 356.103 us; speedup vs baseline: 1.6351x; 1.6351x over previous
//
#include <hip/hip_runtime.h>
#include <float.h>

#define B_   8
#define C_   64
#define N_   4096
#define OUT_ 128
#define KNN  9
#define CAP  128         // append-buffer capacity per row
#define TAU_A 2.3f       // threshold: tau = TAU_A*sigma_n - 64

typedef __attribute__((ext_vector_type(8))) short short8;
typedef __attribute__((ext_vector_type(4))) float f32x4;

__device__ inline unsigned short f2bf(float f) {
    unsigned u = __float_as_uint(f);
    unsigned r = (u + 0x7fffu + ((u >> 16) & 1u)) >> 16;
    return (unsigned short)r;
}
__device__ inline float bf2f(unsigned short s) {
    return __uint_as_float(((unsigned)s) << 16);
}

// ---------------------------------------------------------------------------
// ws layout (bytes):
//   xT:     [B][N][C] float    @ 0          (8388608)
//   xfrag:  hi/lo bf16 chunks  @ 8388608    (8388608)  } idx9 aliases xfrag
//   idx9:   [B*N][9]  int      @ 8388608    (1179648)  } (xfrag dead by refine)
//   x2:     [B][N]    float    @ 16777216   (131072)
//   WT:     [2C][OUT] float    @ 16908288   (65536)
//   cand12: [B*N][12] ushort   @ 16973824   (786432)
//   cnt:    [B*N]     int      @ 17760256   (131072)   total ~17.9 MB
// ---------------------------------------------------------------------------

__global__ void k_wt(const float* __restrict__ W, float* __restrict__ WT) {
    int e = blockIdx.x * 256 + threadIdx.x;
    int o = e >> 7, c = e & 127;
    WT[(size_t)c * OUT_ + o] = W[e];
}

__global__ void k_transpose(const float* __restrict__ x, float* __restrict__ xT,
                            float* __restrict__ x2) {
    __shared__ float t[C_][65];
    int b  = blockIdx.x >> 6;
    int n0 = (blockIdx.x & 63) * 64;
    int tid = threadIdx.x;
    for (int i = 0; i < 16; ++i) {
        int e = i * 256 + tid;
        int c = e >> 6, nn = e & 63;
        t[c][nn] = x[((size_t)b * C_ + c) * N_ + n0 + nn];
    }
    __syncthreads();
    for (int i = 0; i < 16; ++i) {
        int e = i * 256 + tid;
        int nn = e >> 6, c = e & 63;
        xT[((size_t)b * N_ + n0 + nn) * C_ + c] = t[c][nn];
    }
    if (tid < 64) {
        float s = 0.f;
        for (int c = 0; c < C_; ++c) { float v = t[c][tid]; s += v * v; }
        x2[(size_t)b * N_ + n0 + tid] = s;
    }
}

// build bf16 hi/lo fragment chunks from xT (mfma_f32_16x16x32_bf16 load order)
__global__ void k_prep(const float* __restrict__ xT, unsigned short* __restrict__ xfrag) {
    int tid = threadIdx.x;
    int t = blockIdx.x * 2 + (tid >> 7);        // global m-tile 0..2047
    int h = (tid >> 6) & 1;
    int L = tid & 63;
    int b = t >> 8, tb = t & 255;
    int m = tb * 16 + (L & 15);
    int ks = h * 32 + ((L >> 4) * 8);
    const float* src = xT + ((size_t)b * N_ + m) * C_ + ks;
    float4 v0 = *(const float4*)(src);
    float4 v1 = *(const float4*)(src + 4);
    float vs[8] = {v0.x, v0.y, v0.z, v0.w, v1.x, v1.y, v1.z, v1.w};
    short8 hi, lo;
#pragma unroll
    for (int j = 0; j < 8; ++j) {
        unsigned short hb = f2bf(vs[j]);
        float hf = bf2f(hb);
        unsigned short lb = f2bf(vs[j] - hf);
        hi[j] = (short)hb; lo[j] = (short)lb;
    }
    size_t cb = ((size_t)t * 4 + h * 2) * 512;   // ushort units (chunk=512 ushort)
    *(short8*)(xfrag + cb + L * 8)       = hi;
    *(short8*)(xfrag + cb + 512 + L * 8) = lo;
}

// append packed (20-bit sortable key | 12-bit index)
#define APPEND(KEY, TAU, LN, MIDX)                                      \
    if ((KEY) > (TAU)) {                                                \
        unsigned u = __float_as_uint(KEY);                              \
        u = (u & 0x80000000u) ? ~u : (u | 0x80000000u);                 \
        unsigned pk = (u & 0xFFFFF000u) | (unsigned)(MIDX);             \
        int sl = atomicAdd(&cnt_s[LN], 1);                              \
        if (sl < CAP) buf_s[LN][sl] = pk;                               \
    }

// MFMA scan + threshold compaction + in-LDS top-12 selection.
// block = (b = blockIdx&7, ng = blockIdx>>3); 64 n's/block; wave w scans 1024 m's.
__global__ __launch_bounds__(256, 2) void k_topk_mf(const unsigned short* __restrict__ xfrag,
                                                    const float* __restrict__ x2,
                                                    unsigned short* __restrict__ cand12,
                                                    int* __restrict__ cntg) {
    __shared__ int cnt_s[64];
    __shared__ unsigned buf_s[64][CAP];
    int b    = blockIdx.x & 7;
    int ng   = blockIdx.x >> 3;                  // 0..63
    int wave = threadIdx.x >> 6, lane = threadIdx.x & 63;
    if (threadIdx.x < 64) cnt_s[threadIdx.x] = 0;

    const short8* fr = (const short8*)xfrag;     // 16B units; chunk = 64 short8

    short8 Bh[4][2], Bl[4][2];
#pragma unroll
    for (int q = 0; q < 4; ++q)
#pragma unroll
        for (int h = 0; h < 2; ++h) {
            int ch = ((b * 256 + ng * 4 + q) * 4 + h * 2);
            Bh[q][h] = fr[(size_t)ch * 64 + lane];
            Bl[q][h] = fr[(size_t)(ch + 1) * 64 + lane];
        }

    float tau[4];
#pragma unroll
    for (int q = 0; q < 4; ++q) {
        float x2n = x2[b * N_ + ng * 64 + q * 16 + (lane & 15)];
        tau[q] = TAU_A * sqrtf(fmaf(4.f, x2n, 128.f)) - 64.f;
    }

    int mt0 = wave * 64;
    size_t cb = (size_t)(b * 256 + mt0) * 4;
    short8 Ah0 = fr[cb * 64 + lane],       Al0 = fr[(cb + 1) * 64 + lane];
    short8 Ah1 = fr[(cb + 2) * 64 + lane], Al1 = fr[(cb + 3) * 64 + lane];
    f32x4 x2v = *(const f32x4*)(x2 + b * N_ + mt0 * 16 + (lane >> 4) * 4);

    __syncthreads();   // cnt_s zeroed

    for (int i = 0; i < 64; ++i) {
        int inext = (i + 1 < 64) ? i + 1 : i;
        size_t cn = (size_t)(b * 256 + mt0 + inext) * 4;
        short8 nAh0 = fr[cn * 64 + lane],       nAl0 = fr[(cn + 1) * 64 + lane];
        short8 nAh1 = fr[(cn + 2) * 64 + lane], nAl1 = fr[(cn + 3) * 64 + lane];
        f32x4 nx2 = *(const f32x4*)(x2 + b * N_ + (mt0 + inext) * 16 + (lane >> 4) * 4);

        int mbase = (mt0 + i) * 16 + (lane >> 4) * 4;

#pragma unroll
        for (int q = 0; q < 4; ++q) {
            f32x4 acc = {0.f, 0.f, 0.f, 0.f};
            acc = __builtin_amdgcn_mfma_f32_16x16x32_bf16(Ah0, Bh[q][0], acc, 0, 0, 0);
            acc = __builtin_amdgcn_mfma_f32_16x16x32_bf16(Ah1, Bh[q][1], acc, 0, 0, 0);
            acc = __builtin_amdgcn_mfma_f32_16x16x32_bf16(Al0, Bh[q][0], acc, 0, 0, 0);
            acc = __builtin_amdgcn_mfma_f32_16x16x32_bf16(Al1, Bh[q][1], acc, 0, 0, 0);
            acc = __builtin_amdgcn_mfma_f32_16x16x32_bf16(Ah0, Bl[q][0], acc, 0, 0, 0);
            acc = __builtin_amdgcn_mfma_f32_16x16x32_bf16(Ah1, Bl[q][1], acc, 0, 0, 0);
            float k0 = fmaf(2.f, acc[0], -x2v[0]);
            float k1 = fmaf(2.f, acc[1], -x2v[1]);
            float k2 = fmaf(2.f, acc[2], -x2v[2]);
            float k3 = fmaf(2.f, acc[3], -x2v[3]);
            int ln = q * 16 + (lane & 15);
            APPEND(k0, tau[q], ln, mbase + 0)
            APPEND(k1, tau[q], ln, mbase + 1)
            APPEND(k2, tau[q], ln, mbase + 2)
            APPEND(k3, tau[q], ln, mbase + 3)
        }
        Ah0 = nAh0; Al0 = nAl0; Ah1 = nAh1; Al1 = nAl1; x2v = nx2;
    }

    __syncthreads();
    // per-row top-12 of the packed keys (data is in LDS; 1 thread/row)
    if (threadIdx.x < 64) {
        int r = threadIdx.x;
        int c = cnt_s[r];
        size_t grow = (size_t)b * N_ + ng * 64 + r;
        cntg[grow] = c;
        int cc = min(c, CAP);
        unsigned best[12];                       // ascending; best[0] = smallest
#pragma unroll
        for (int j = 0; j < 12; ++j) best[j] = 0u;
        for (int s = 0; s < cc; ++s) {
            unsigned v = buf_s[r][s];
            if (v > best[0]) {
                best[0] = v;
#pragma unroll
                for (int j = 0; j < 11; ++j) {
                    bool sw = best[j] > best[j + 1];
                    unsigned t = best[j];
                    best[j]     = sw ? best[j + 1] : best[j];
                    best[j + 1] = sw ? t : best[j + 1];
                }
            }
        }
#pragma unroll
        for (int j = 0; j < 12; ++j)
            cand12[grow * 12 + j] = (unsigned short)(best[11 - j] & 0xFFFu);
    }
}

// exact fp64 re-rank of the 12 coarse-selected candidates -> true top-9.
// 2 rows per wave (half-wave each), 8 rows per block.
__global__ void k_refine(const float* __restrict__ xT, const unsigned short* __restrict__ cand12,
                         const int* __restrict__ cntg, int* __restrict__ idx9) {
    int wave = threadIdx.x >> 6, lane = threadIdx.x & 63;
    int half = lane >> 5, hl = lane & 31;
    int row = blockIdx.x * 8 + wave * 2 + half;
    int cnt = cntg[row];
    bool ok = (cnt >= KNN && cnt <= CAP);
    int cnt12 = min(cnt, 12);
    int b = row >> 12;

    double mykey = -1e300; int myidx = 0x7fffffff;
    if (ok && hl < cnt12) {
        int m = cand12[(size_t)row * 12 + hl];
        const float* xi = xT + (size_t)row * C_;
        const float* xm = xT + (((size_t)b << 12) + m) * C_;
        double d = 0.0, s2 = 0.0;
#pragma unroll
        for (int c4 = 0; c4 < 16; ++c4) {
            float4 a = *(const float4*)(xi + c4 * 4);
            float4 v = *(const float4*)(xm + c4 * 4);
            d = fma((double)a.x, (double)v.x, d);  s2 = fma((double)v.x, (double)v.x, s2);
            d = fma((double)a.y, (double)v.y, d);  s2 = fma((double)v.y, (double)v.y, s2);
            d = fma((double)a.z, (double)v.z, d);  s2 = fma((double)v.z, (double)v.z, s2);
            d = fma((double)a.w, (double)v.w, d);  s2 = fma((double)v.w, (double)v.w, s2);
        }
        mykey = 2.0 * d - s2;
        myidx = m;
    }
    for (int r = 0; r < KNN; ++r) {
        double k = mykey; int ix = myidx;
#pragma unroll
        for (int o = 16; o; o >>= 1) {           // half-wave butterfly
            double ok2 = __shfl_xor(k, o); int oi = __shfl_xor(ix, o);
            bool take = (ok2 > k) || (ok2 == k && oi < ix);
            k = take ? ok2 : k; ix = take ? oi : ix;
        }
        if (ok && hl == 0) idx9[(size_t)row * KNN + r] = ix;
        if (myidx == ix) { mykey = -1e300; myidx = 0x7fffffff; }  // unique per row
    }
}

// exact fp64 full scan for rows where the threshold buffer failed (near-never)
__global__ void k_fallback(const float* __restrict__ xT, const int* __restrict__ cntg,
                           int* __restrict__ idx9) {
    int wave = threadIdx.x >> 6, lane = threadIdx.x & 63;
    int w = blockIdx.x * 4 + wave;
    for (int rr = 0; rr < 16; ++rr) {
        int row = w * 16 + rr;
        int cnt = cntg[row];
        if (cnt >= KNN && cnt <= CAP) continue;
        int b = row >> 12;
        const float* xi = xT + (size_t)row * C_;
        double sk[9]; int si[9];
#pragma unroll
        for (int j = 0; j < 9; ++j) { sk[j] = -1e300; si[j] = 0x7fffffff; }
        for (int mb = 0; mb < N_; mb += 64) {
            int m = mb + lane;
            const float* xm = xT + (((size_t)b << 12) + m) * C_;
            double d = 0.0, s2 = 0.0;
            for (int c = 0; c < C_; ++c) {
                double v = xm[c];
                d += (double)xi[c] * v; s2 += v * v;
            }
            double key = 2.0 * d - s2;
            if (key > sk[0] || (key == sk[0] && m < si[0])) {
                sk[0] = key; si[0] = m;
#pragma unroll
                for (int j = 0; j < 8; ++j) {
                    bool sw = (sk[j] > sk[j + 1]) || (sk[j] == sk[j + 1] && si[j] < si[j + 1]);
                    double tk = sk[j]; int ti = si[j];
                    sk[j]     = sw ? sk[j + 1] : sk[j];
                    si[j]     = sw ? si[j + 1] : si[j];
                    sk[j + 1] = sw ? tk : sk[j + 1];
                    si[j + 1] = sw ? ti : si[j + 1];
                }
            }
        }
        for (int r = 0; r < KNN; ++r) {
            double k = sk[8]; int ix = si[8];
#pragma unroll
            for (int o = 32; o; o >>= 1) {
                double ok = __shfl_xor(k, o); int oi = __shfl_xor(ix, o);
                bool take = (ok > k) || (ok == k && oi < ix);
                k = take ? ok : k; ix = take ? oi : ix;
            }
            if (lane == 0) idx9[(size_t)row * KNN + r] = ix;
            if (si[8] == ix) {
#pragma unroll
                for (int j = 8; j > 0; --j) { sk[j] = sk[j - 1]; si[j] = si[j - 1]; }
                sk[0] = -1e300; si[0] = 0x7fffffff;
            }
        }
    }
}

// fused: gather-max (x_j - x_i) into LDS h-tile, then 1x1 conv + bias + ReLU
__global__ void k_gemm(const float* __restrict__ xT, const int* __restrict__ idx9,
                       const float* __restrict__ WT, const float* __restrict__ bias,
                       float* __restrict__ out) {
    __shared__ float h[64][129];
    int b  = blockIdx.x >> 6;
    int n0 = (blockIdx.x & 63) * 64;
    int wave = threadIdx.x >> 6, lane = threadIdx.x & 63;
    for (int r = 0; r < 16; ++r) {
        int nn = wave * 16 + r;
        size_t row = (size_t)b * N_ + n0 + nn;
        const int* id = idx9 + row * KNN;
        float m = -FLT_MAX;
#pragma unroll
        for (int k = 0; k < KNN; ++k) {
            int j = id[k];
            m = fmaxf(m, xT[(((size_t)b << 12) + j) * C_ + lane]);
        }
        float xic = xT[row * C_ + lane];
        h[nn][lane]      = xic;
        h[nn][64 + lane] = m - xic;
    }
    __syncthreads();
    int o0 = wave * 32;
    float acc[32];
#pragma unroll
    for (int j = 0; j < 32; ++j) acc[j] = 0.f;
    for (int c = 0; c < 2 * C_; ++c) {
        float hv = h[lane][c];
        const float4* wrow = (const float4*)(WT + (size_t)c * OUT_ + o0);
#pragma unroll
        for (int j4 = 0; j4 < 8; ++j4) {
            float4 w = wrow[j4];
            acc[j4 * 4 + 0] += w.x * hv;
            acc[j4 * 4 + 1] += w.y * hv;
            acc[j4 * 4 + 2] += w.z * hv;
            acc[j4 * 4 + 3] += w.w * hv;
        }
    }
#pragma unroll
    for (int j = 0; j < 32; ++j) {
        float v = acc[j] + bias[o0 + j];
        v = fmaxf(v, 0.f);
        out[((size_t)b * OUT_ + o0 + j) * N_ + n0 + lane] = v;
    }
}

extern "C" void kernel_launch(void* const* d_in, const int* in_sizes, int n_in,
                              void* d_out, int out_size, void* d_ws, size_t ws_size,
                              hipStream_t stream) {
    const float* x    = (const float*)d_in[0];
    const float* W    = (const float*)d_in[1];
    const float* bias = (const float*)d_in[2];
    float* out = (float*)d_out;
    char* ws = (char*)d_ws;

    float*          xT     = (float*)(ws);
    unsigned short* xfrag  = (unsigned short*)(ws + 8388608);
    int*            idx9   = (int*)(ws + 8388608);        // aliases xfrag (dead by refine)
    float*          x2     = (float*)(ws + 16777216);
    float*          WT     = (float*)(ws + 16908288);
    unsigned short* cand12 = (unsigned short*)(ws + 16973824);
    int*            cnt    = (int*)(ws + 17760256);

    k_wt       <<<dim3(64),   dim3(256), 0, stream>>>(W, WT);
    k_transpose<<<dim3(512),  dim3(256), 0, stream>>>(x, xT, x2);
    k_prep     <<<dim3(1024), dim3(256), 0, stream>>>(xT, xfrag);
    k_topk_mf  <<<dim3(512),  dim3(256), 0, stream>>>(xfrag, x2, cand12, cnt);
    k_refine   <<<dim3(4096), dim3(256), 0, stream>>>(xT, cand12, cnt, idx9);
    k_fallback <<<dim3(512),  dim3(256), 0, stream>>>(xT, cnt, idx9);
    k_gemm     <<<dim3(512),  dim3(256), 0, stream>>>(xT, idx9, WT, bias, out);
}

// Round 7
// 221.154 us; speedup vs baseline: 2.6328x; 1.6102x over previous
//
#include <hip/hip_runtime.h>
#include <float.h>

#define B_   8
#define C_   64
#define N_   4096
#define OUT_ 128
#define KNN  9
#define CAP  256         // append-buffer capacity per row
#define TAU_A 2.0f       // threshold: tau = TAU_A*sigma_n - 64 (margin for chi2 thin tail)

typedef __attribute__((ext_vector_type(8))) short short8;
typedef __attribute__((ext_vector_type(4))) float f32x4;

__device__ inline unsigned short f2bf(float f) {
    unsigned u = __float_as_uint(f);
    unsigned r = (u + 0x7fffu + ((u >> 16) & 1u)) >> 16;
    return (unsigned short)r;
}
__device__ inline float bf2f(unsigned short s) {
    return __uint_as_float(((unsigned)s) << 16);
}

// ---------------------------------------------------------------------------
// ws layout (bytes):
//   xT:     [B][N][C] float    @ 0          (8388608)
//   xfrag:  hi/lo bf16 chunks  @ 8388608    (8388608)  } idx9 aliases xfrag
//   idx9:   [B*N][9]  int      @ 8388608    (1179648)  } (xfrag dead by refine)
//   x2:     [B][N]    float    @ 16777216   (131072)
//   WT:     [2C][OUT] float    @ 16908288   (65536)
//   cand12: [B*N][12] ushort   @ 16973824   (786432)
//   cnt:    [B*N]     int      @ 17760256   (131072)   total ~17.9 MB
// ---------------------------------------------------------------------------

__global__ void k_wt(const float* __restrict__ W, float* __restrict__ WT) {
    int e = blockIdx.x * 256 + threadIdx.x;
    int o = e >> 7, c = e & 127;
    WT[(size_t)c * OUT_ + o] = W[e];
}

__global__ void k_transpose(const float* __restrict__ x, float* __restrict__ xT,
                            float* __restrict__ x2) {
    __shared__ float t[C_][65];
    int b  = blockIdx.x >> 6;
    int n0 = (blockIdx.x & 63) * 64;
    int tid = threadIdx.x;
    for (int i = 0; i < 16; ++i) {
        int e = i * 256 + tid;
        int c = e >> 6, nn = e & 63;
        t[c][nn] = x[((size_t)b * C_ + c) * N_ + n0 + nn];
    }
    __syncthreads();
    for (int i = 0; i < 16; ++i) {
        int e = i * 256 + tid;
        int nn = e >> 6, c = e & 63;
        xT[((size_t)b * N_ + n0 + nn) * C_ + c] = t[c][nn];
    }
    if (tid < 64) {
        float s = 0.f;
        for (int c = 0; c < C_; ++c) { float v = t[c][tid]; s += v * v; }
        x2[(size_t)b * N_ + n0 + tid] = s;
    }
}

// build bf16 hi/lo fragment chunks from xT (mfma_f32_16x16x32_bf16 load order)
__global__ void k_prep(const float* __restrict__ xT, unsigned short* __restrict__ xfrag) {
    int tid = threadIdx.x;
    int t = blockIdx.x * 2 + (tid >> 7);        // global m-tile 0..2047
    int h = (tid >> 6) & 1;
    int L = tid & 63;
    int b = t >> 8, tb = t & 255;
    int m = tb * 16 + (L & 15);
    int ks = h * 32 + ((L >> 4) * 8);
    const float* src = xT + ((size_t)b * N_ + m) * C_ + ks;
    float4 v0 = *(const float4*)(src);
    float4 v1 = *(const float4*)(src + 4);
    float vs[8] = {v0.x, v0.y, v0.z, v0.w, v1.x, v1.y, v1.z, v1.w};
    short8 hi, lo;
#pragma unroll
    for (int j = 0; j < 8; ++j) {
        unsigned short hb = f2bf(vs[j]);
        float hf = bf2f(hb);
        unsigned short lb = f2bf(vs[j] - hf);
        hi[j] = (short)hb; lo[j] = (short)lb;
    }
    size_t cb = ((size_t)t * 4 + h * 2) * 512;   // ushort units (chunk=512 ushort)
    *(short8*)(xfrag + cb + L * 8)       = hi;
    *(short8*)(xfrag + cb + 512 + L * 8) = lo;
}

// append packed (20-bit sortable key | 12-bit index)
#define APPEND(KEY, TAU, LN, MIDX)                                      \
    if ((KEY) > (TAU)) {                                                \
        unsigned u = __float_as_uint(KEY);                              \
        u = (u & 0x80000000u) ? ~u : (u | 0x80000000u);                 \
        unsigned pk = (u & 0xFFFFF000u) | (unsigned)(MIDX);             \
        int sl = atomicAdd(&cnt_s[LN], 1);                              \
        if (sl < CAP) buf_s[LN][sl] = pk;                               \
    }

// MFMA scan + threshold compaction + in-LDS top-12 selection.
// block = (b = blockIdx&7, ng = blockIdx>>3); 64 n's/block; wave w scans 1024 m's.
__global__ __launch_bounds__(256, 2) void k_topk_mf(const unsigned short* __restrict__ xfrag,
                                                    const float* __restrict__ x2,
                                                    unsigned short* __restrict__ cand12,
                                                    int* __restrict__ cntg) {
    __shared__ int cnt_s[64];
    __shared__ unsigned buf_s[64][CAP];
    int b    = blockIdx.x & 7;
    int ng   = blockIdx.x >> 3;                  // 0..63
    int wave = threadIdx.x >> 6, lane = threadIdx.x & 63;
    if (threadIdx.x < 64) cnt_s[threadIdx.x] = 0;

    const short8* fr = (const short8*)xfrag;     // 16B units; chunk = 64 short8

    short8 Bh[4][2], Bl[4][2];
#pragma unroll
    for (int q = 0; q < 4; ++q)
#pragma unroll
        for (int h = 0; h < 2; ++h) {
            int ch = ((b * 256 + ng * 4 + q) * 4 + h * 2);
            Bh[q][h] = fr[(size_t)ch * 64 + lane];
            Bl[q][h] = fr[(size_t)(ch + 1) * 64 + lane];
        }

    float tau[4];
#pragma unroll
    for (int q = 0; q < 4; ++q) {
        float x2n = x2[b * N_ + ng * 64 + q * 16 + (lane & 15)];
        tau[q] = TAU_A * sqrtf(fmaf(4.f, x2n, 128.f)) - 64.f;
    }

    int mt0 = wave * 64;
    size_t cb = (size_t)(b * 256 + mt0) * 4;
    short8 Ah0 = fr[cb * 64 + lane],       Al0 = fr[(cb + 1) * 64 + lane];
    short8 Ah1 = fr[(cb + 2) * 64 + lane], Al1 = fr[(cb + 3) * 64 + lane];
    f32x4 x2v = *(const f32x4*)(x2 + b * N_ + mt0 * 16 + (lane >> 4) * 4);

    __syncthreads();   // cnt_s zeroed

    for (int i = 0; i < 64; ++i) {
        int inext = (i + 1 < 64) ? i + 1 : i;
        size_t cn = (size_t)(b * 256 + mt0 + inext) * 4;
        short8 nAh0 = fr[cn * 64 + lane],       nAl0 = fr[(cn + 1) * 64 + lane];
        short8 nAh1 = fr[(cn + 2) * 64 + lane], nAl1 = fr[(cn + 3) * 64 + lane];
        f32x4 nx2 = *(const f32x4*)(x2 + b * N_ + (mt0 + inext) * 16 + (lane >> 4) * 4);

        int mbase = (mt0 + i) * 16 + (lane >> 4) * 4;

#pragma unroll
        for (int q = 0; q < 4; ++q) {
            f32x4 acc = {0.f, 0.f, 0.f, 0.f};
            acc = __builtin_amdgcn_mfma_f32_16x16x32_bf16(Ah0, Bh[q][0], acc, 0, 0, 0);
            acc = __builtin_amdgcn_mfma_f32_16x16x32_bf16(Ah1, Bh[q][1], acc, 0, 0, 0);
            acc = __builtin_amdgcn_mfma_f32_16x16x32_bf16(Al0, Bh[q][0], acc, 0, 0, 0);
            acc = __builtin_amdgcn_mfma_f32_16x16x32_bf16(Al1, Bh[q][1], acc, 0, 0, 0);
            acc = __builtin_amdgcn_mfma_f32_16x16x32_bf16(Ah0, Bl[q][0], acc, 0, 0, 0);
            acc = __builtin_amdgcn_mfma_f32_16x16x32_bf16(Ah1, Bl[q][1], acc, 0, 0, 0);
            float k0 = fmaf(2.f, acc[0], -x2v[0]);
            float k1 = fmaf(2.f, acc[1], -x2v[1]);
            float k2 = fmaf(2.f, acc[2], -x2v[2]);
            float k3 = fmaf(2.f, acc[3], -x2v[3]);
            int ln = q * 16 + (lane & 15);
            APPEND(k0, tau[q], ln, mbase + 0)
            APPEND(k1, tau[q], ln, mbase + 1)
            APPEND(k2, tau[q], ln, mbase + 2)
            APPEND(k3, tau[q], ln, mbase + 3)
        }
        Ah0 = nAh0; Al0 = nAl0; Ah1 = nAh1; Al1 = nAl1; x2v = nx2;
    }

    __syncthreads();
    // per-row top-12 of the packed keys (data is in LDS; 1 thread/row)
    if (threadIdx.x < 64) {
        int r = threadIdx.x;
        int c = cnt_s[r];
        size_t grow = (size_t)b * N_ + ng * 64 + r;
        cntg[grow] = c;
        int cc = min(c, CAP);
        unsigned best[12];                       // ascending; best[0] = smallest
#pragma unroll
        for (int j = 0; j < 12; ++j) best[j] = 0u;
        for (int s = 0; s < cc; ++s) {
            unsigned v = buf_s[r][s];
            if (v > best[0]) {
                best[0] = v;
#pragma unroll
                for (int j = 0; j < 11; ++j) {
                    bool sw = best[j] > best[j + 1];
                    unsigned t = best[j];
                    best[j]     = sw ? best[j + 1] : best[j];
                    best[j + 1] = sw ? t : best[j + 1];
                }
            }
        }
#pragma unroll
        for (int j = 0; j < 12; ++j)
            cand12[grow * 12 + j] = (unsigned short)(best[11 - j] & 0xFFFu);
    }
}

// exact fp64 re-rank of the 12 coarse-selected candidates -> true top-9.
// 2 rows per wave (half-wave each), 8 rows per block.
__global__ void k_refine(const float* __restrict__ xT, const unsigned short* __restrict__ cand12,
                         const int* __restrict__ cntg, int* __restrict__ idx9) {
    int wave = threadIdx.x >> 6, lane = threadIdx.x & 63;
    int half = lane >> 5, hl = lane & 31;
    int row = blockIdx.x * 8 + wave * 2 + half;
    int cnt = cntg[row];
    bool ok = (cnt >= KNN && cnt <= CAP);
    int cnt12 = min(cnt, 12);
    int b = row >> 12;

    double mykey = -1e300; int myidx = 0x7fffffff;
    if (ok && hl < cnt12) {
        int m = cand12[(size_t)row * 12 + hl];
        const float* xi = xT + (size_t)row * C_;
        const float* xm = xT + (((size_t)b << 12) + m) * C_;
        double d = 0.0, s2 = 0.0;
#pragma unroll
        for (int c4 = 0; c4 < 16; ++c4) {
            float4 a = *(const float4*)(xi + c4 * 4);
            float4 v = *(const float4*)(xm + c4 * 4);
            d = fma((double)a.x, (double)v.x, d);  s2 = fma((double)v.x, (double)v.x, s2);
            d = fma((double)a.y, (double)v.y, d);  s2 = fma((double)v.y, (double)v.y, s2);
            d = fma((double)a.z, (double)v.z, d);  s2 = fma((double)v.z, (double)v.z, s2);
            d = fma((double)a.w, (double)v.w, d);  s2 = fma((double)v.w, (double)v.w, s2);
        }
        mykey = 2.0 * d - s2;
        myidx = m;
    }
    for (int r = 0; r < KNN; ++r) {
        double k = mykey; int ix = myidx;
#pragma unroll
        for (int o = 16; o; o >>= 1) {           // half-wave butterfly
            double ok2 = __shfl_xor(k, o); int oi = __shfl_xor(ix, o);
            bool take = (ok2 > k) || (ok2 == k && oi < ix);
            k = take ? ok2 : k; ix = take ? oi : ix;
        }
        if (ok && hl == 0) idx9[(size_t)row * KNN + r] = ix;
        if (myidx == ix) { mykey = -1e300; myidx = 0x7fffffff; }  // unique per row
    }
}

// exact fp64 full scan for rows where the threshold buffer failed (insurance).
// One wave per row, early-exit; xi in registers; float4 loads; split fp64 chains.
__global__ void k_fallback(const float* __restrict__ xT, const int* __restrict__ cntg,
                           int* __restrict__ idx9) {
    int wave = threadIdx.x >> 6, lane = threadIdx.x & 63;
    int row = blockIdx.x * 4 + wave;            // grid 8192 * 4 waves = 32768 rows
    int cnt = cntg[row];
    if (cnt >= KNN && cnt <= CAP) return;
    int b = row >> 12;
    const float* xi = xT + (size_t)row * C_;
    float4 xr[16];
#pragma unroll
    for (int c4 = 0; c4 < 16; ++c4) xr[c4] = *(const float4*)(xi + c4 * 4);
    double sk[9]; int si[9];
#pragma unroll
    for (int j = 0; j < 9; ++j) { sk[j] = -1e300; si[j] = 0x7fffffff; }
    for (int mb = 0; mb < N_; mb += 64) {
        int m = mb + lane;
        const float* xm = xT + (((size_t)b << 12) + m) * C_;
        double d0 = 0.0, d1 = 0.0, s0 = 0.0, s1 = 0.0;
#pragma unroll
        for (int c4 = 0; c4 < 16; c4 += 2) {
            float4 v = *(const float4*)(xm + c4 * 4);
            float4 w = *(const float4*)(xm + c4 * 4 + 4);
            float4 a = xr[c4], bb = xr[c4 + 1];
            d0 = fma((double)a.x, (double)v.x, d0);  s0 = fma((double)v.x, (double)v.x, s0);
            d0 = fma((double)a.y, (double)v.y, d0);  s0 = fma((double)v.y, (double)v.y, s0);
            d0 = fma((double)a.z, (double)v.z, d0);  s0 = fma((double)v.z, (double)v.z, s0);
            d0 = fma((double)a.w, (double)v.w, d0);  s0 = fma((double)v.w, (double)v.w, s0);
            d1 = fma((double)bb.x, (double)w.x, d1); s1 = fma((double)w.x, (double)w.x, s1);
            d1 = fma((double)bb.y, (double)w.y, d1); s1 = fma((double)w.y, (double)w.y, s1);
            d1 = fma((double)bb.z, (double)w.z, d1); s1 = fma((double)w.z, (double)w.z, s1);
            d1 = fma((double)bb.w, (double)w.w, d1); s1 = fma((double)w.w, (double)w.w, s1);
        }
        double key = 2.0 * (d0 + d1) - (s0 + s1);
        if (key > sk[0] || (key == sk[0] && m < si[0])) {
            sk[0] = key; si[0] = m;
#pragma unroll
            for (int j = 0; j < 8; ++j) {
                bool sw = (sk[j] > sk[j + 1]) || (sk[j] == sk[j + 1] && si[j] < si[j + 1]);
                double tk = sk[j]; int ti = si[j];
                sk[j]     = sw ? sk[j + 1] : sk[j];
                si[j]     = sw ? si[j + 1] : si[j];
                sk[j + 1] = sw ? tk : sk[j + 1];
                si[j + 1] = sw ? ti : si[j + 1];
            }
        }
    }
    for (int r = 0; r < KNN; ++r) {
        double k = sk[8]; int ix = si[8];
#pragma unroll
        for (int o = 32; o; o >>= 1) {
            double ok = __shfl_xor(k, o); int oi = __shfl_xor(ix, o);
            bool take = (ok > k) || (ok == k && oi < ix);
            k = take ? ok : k; ix = take ? oi : ix;
        }
        if (lane == 0) idx9[(size_t)row * KNN + r] = ix;
        if (si[8] == ix) {
#pragma unroll
            for (int j = 8; j > 0; --j) { sk[j] = sk[j - 1]; si[j] = si[j - 1]; }
            sk[0] = -1e300; si[0] = 0x7fffffff;
        }
    }
}

// fused: gather-max (x_j - x_i) into LDS h-tile, then 1x1 conv + bias + ReLU
__global__ void k_gemm(const float* __restrict__ xT, const int* __restrict__ idx9,
                       const float* __restrict__ WT, const float* __restrict__ bias,
                       float* __restrict__ out) {
    __shared__ float h[64][129];
    int b  = blockIdx.x >> 6;
    int n0 = (blockIdx.x & 63) * 64;
    int wave = threadIdx.x >> 6, lane = threadIdx.x & 63;
    for (int r = 0; r < 16; ++r) {
        int nn = wave * 16 + r;
        size_t row = (size_t)b * N_ + n0 + nn;
        const int* id = idx9 + row * KNN;
        float m = -FLT_MAX;
#pragma unroll
        for (int k = 0; k < KNN; ++k) {
            int j = id[k];
            m = fmaxf(m, xT[(((size_t)b << 12) + j) * C_ + lane]);
        }
        float xic = xT[row * C_ + lane];
        h[nn][lane]      = xic;
        h[nn][64 + lane] = m - xic;
    }
    __syncthreads();
    int o0 = wave * 32;
    float acc[32];
#pragma unroll
    for (int j = 0; j < 32; ++j) acc[j] = 0.f;
    for (int c = 0; c < 2 * C_; ++c) {
        float hv = h[lane][c];
        const float4* wrow = (const float4*)(WT + (size_t)c * OUT_ + o0);
#pragma unroll
        for (int j4 = 0; j4 < 8; ++j4) {
            float4 w = wrow[j4];
            acc[j4 * 4 + 0] += w.x * hv;
            acc[j4 * 4 + 1] += w.y * hv;
            acc[j4 * 4 + 2] += w.z * hv;
            acc[j4 * 4 + 3] += w.w * hv;
        }
    }
#pragma unroll
    for (int j = 0; j < 32; ++j) {
        float v = acc[j] + bias[o0 + j];
        v = fmaxf(v, 0.f);
        out[((size_t)b * OUT_ + o0 + j) * N_ + n0 + lane] = v;
    }
}

extern "C" void kernel_launch(void* const* d_in, const int* in_sizes, int n_in,
                              void* d_out, int out_size, void* d_ws, size_t ws_size,
                              hipStream_t stream) {
    const float* x    = (const float*)d_in[0];
    const float* W    = (const float*)d_in[1];
    const float* bias = (const float*)d_in[2];
    float* out = (float*)d_out;
    char* ws = (char*)d_ws;

    float*          xT     = (float*)(ws);
    unsigned short* xfrag  = (unsigned short*)(ws + 8388608);
    int*            idx9   = (int*)(ws + 8388608);        // aliases xfrag (dead by refine)
    float*          x2     = (float*)(ws + 16777216);
    float*          WT     = (float*)(ws + 16908288);
    unsigned short* cand12 = (unsigned short*)(ws + 16973824);
    int*            cnt    = (int*)(ws + 17760256);

    k_wt       <<<dim3(64),   dim3(256), 0, stream>>>(W, WT);
    k_transpose<<<dim3(512),  dim3(256), 0, stream>>>(x, xT, x2);
    k_prep     <<<dim3(1024), dim3(256), 0, stream>>>(xT, xfrag);
    k_topk_mf  <<<dim3(512),  dim3(256), 0, stream>>>(xfrag, x2, cand12, cnt);
    k_refine   <<<dim3(4096), dim3(256), 0, stream>>>(xT, cand12, cnt, idx9);
    k_fallback <<<dim3(8192), dim3(256), 0, stream>>>(xT, cnt, idx9);
    k_gemm     <<<dim3(512),  dim3(256), 0, stream>>>(xT, idx9, WT, bias, out);
}

// Round 8
// 218.886 us; speedup vs baseline: 2.6601x; 1.0104x over previous
//
#include <hip/hip_runtime.h>
#include <float.h>

#define B_   8
#define C_   64
#define N_   4096
#define OUT_ 128
#define KNN  9
#define CAP  128         // append-buffer capacity per row (overflow -> exact fallback)
#define TAU_A 2.0f       // threshold: tau = TAU_A*sigma_n - 64

typedef __attribute__((ext_vector_type(8))) short short8;
typedef __attribute__((ext_vector_type(4))) float f32x4;

__device__ inline unsigned short f2bf(float f) {
    unsigned u = __float_as_uint(f);
    unsigned r = (u + 0x7fffu + ((u >> 16) & 1u)) >> 16;
    return (unsigned short)r;
}
__device__ inline float bf2f(unsigned short s) {
    return __uint_as_float(((unsigned)s) << 16);
}

// ---------------------------------------------------------------------------
// ws layout (bytes):
//   xT:     [B][N][C] float    @ 0          (8388608)
//   xfrag:  hi/lo bf16 chunks  @ 8388608    (8388608)  } idx9 aliases xfrag
//   idx9:   [B*N][9]  int      @ 8388608    (1179648)  } (xfrag dead by refine)
//   x2:     [B][N]    float    @ 16777216   (131072)
//   WT:     [2C][OUT] float    @ 16908288   (65536)
//   cand12: [B*N][12] ushort   @ 16973824   (786432)
//   cnt:    [B*N]     int      @ 17760256   (131072)   total ~17.9 MB
// ---------------------------------------------------------------------------

__global__ void k_wt(const float* __restrict__ W, float* __restrict__ WT) {
    int e = blockIdx.x * 256 + threadIdx.x;
    int o = e >> 7, c = e & 127;
    WT[(size_t)c * OUT_ + o] = W[e];
}

// transpose + x2 + bf16 hi/lo fragment build (fused; k_prep eliminated)
__global__ void k_transpose(const float* __restrict__ x, float* __restrict__ xT,
                            float* __restrict__ x2, unsigned short* __restrict__ xfrag) {
    __shared__ float t[C_][65];
    int b  = blockIdx.x >> 6;
    int n0 = (blockIdx.x & 63) * 64;
    int tid = threadIdx.x;
    for (int i = 0; i < 16; ++i) {
        int e = i * 256 + tid;
        int c = e >> 6, nn = e & 63;
        t[c][nn] = x[((size_t)b * C_ + c) * N_ + n0 + nn];
    }
    __syncthreads();
    for (int i = 0; i < 16; ++i) {
        int e = i * 256 + tid;
        int nn = e >> 6, c = e & 63;
        xT[((size_t)b * N_ + n0 + nn) * C_ + c] = t[c][nn];
    }
    // fragments: q = local m-tile (16 n's), L = lane slot in chunk
    int q = tid >> 6, L = tid & 63;
    int mloc = q * 16 + (L & 15);
    int k8 = (L >> 4) * 8;
    size_t cb = (size_t)(b * 256 + (n0 >> 4) + q) * 4 * 512;   // ushort units
#pragma unroll
    for (int h = 0; h < 2; ++h) {
        short8 hi, lo;
#pragma unroll
        for (int j = 0; j < 8; ++j) {
            float v = t[h * 32 + k8 + j][mloc];
            unsigned short hb = f2bf(v);
            float hf = bf2f(hb);
            unsigned short lb = f2bf(v - hf);
            hi[j] = (short)hb; lo[j] = (short)lb;
        }
        *(short8*)(xfrag + cb + (h * 2 + 0) * 512 + L * 8) = hi;
        *(short8*)(xfrag + cb + (h * 2 + 1) * 512 + L * 8) = lo;
    }
    if (tid < 64) {
        float s = 0.f;
        for (int c = 0; c < C_; ++c) { float v = t[c][tid]; s += v * v; }
        x2[(size_t)b * N_ + n0 + tid] = s;
    }
}

// append packed (20-bit sortable key | 12-bit index)
#define APPEND(KEY, TAU, LN, MIDX)                                      \
    if ((KEY) > (TAU)) {                                                \
        unsigned u = __float_as_uint(KEY);                              \
        u = (u & 0x80000000u) ? ~u : (u | 0x80000000u);                 \
        unsigned pk = (u & 0xFFFFF000u) | (unsigned)(MIDX);             \
        int sl = atomicAdd(&cnt_s[LN], 1);                              \
        if (sl < CAP) buf_s[LN][sl] = pk;                               \
    }

// MFMA scan + threshold compaction + in-LDS top-12 selection.
// block = (b = blockIdx&7, ng = blockIdx>>3); 64 n's/block; wave w scans 1024 m's.
// LDS ~33 KB -> 4 blocks/CU for latency hiding.
__global__ __launch_bounds__(256, 4) void k_topk_mf(const unsigned short* __restrict__ xfrag,
                                                    const float* __restrict__ x2,
                                                    unsigned short* __restrict__ cand12,
                                                    int* __restrict__ cntg) {
    __shared__ int cnt_s[64];
    __shared__ unsigned buf_s[64][CAP];
    int b    = blockIdx.x & 7;
    int ng   = blockIdx.x >> 3;                  // 0..63
    int wave = threadIdx.x >> 6, lane = threadIdx.x & 63;
    if (threadIdx.x < 64) cnt_s[threadIdx.x] = 0;

    const short8* fr = (const short8*)xfrag;     // 16B units; chunk = 64 short8

    short8 Bh[4][2], Bl[4][2];
#pragma unroll
    for (int q = 0; q < 4; ++q)
#pragma unroll
        for (int h = 0; h < 2; ++h) {
            int ch = ((b * 256 + ng * 4 + q) * 4 + h * 2);
            Bh[q][h] = fr[(size_t)ch * 64 + lane];
            Bl[q][h] = fr[(size_t)(ch + 1) * 64 + lane];
        }

    float tau[4];
#pragma unroll
    for (int q = 0; q < 4; ++q) {
        float x2n = x2[b * N_ + ng * 64 + q * 16 + (lane & 15)];
        tau[q] = TAU_A * sqrtf(fmaf(4.f, x2n, 128.f)) - 64.f;
    }

    int mt0 = wave * 64;
    const short8* pA = fr + (size_t)(b * 256 + mt0) * 4 * 64 + lane;
    const f32x4*  px2 = (const f32x4*)(x2 + b * N_ + mt0 * 16 + (lane >> 4) * 4);
    short8 Ah0 = pA[0], Al0 = pA[64], Ah1 = pA[128], Al1 = pA[192];
    f32x4 x2v = *px2;

    __syncthreads();   // cnt_s zeroed

    for (int i = 0; i < 64; ++i) {
        if (i != 63) { pA += 256; px2 += 4; }
        short8 nAh0 = pA[0], nAl0 = pA[64], nAh1 = pA[128], nAl1 = pA[192];
        f32x4 nx2 = *px2;

        int mbase = (mt0 + i) * 16 + (lane >> 4) * 4;

#pragma unroll
        for (int q = 0; q < 4; ++q) {
            f32x4 acc = {0.f, 0.f, 0.f, 0.f};
            acc = __builtin_amdgcn_mfma_f32_16x16x32_bf16(Ah0, Bh[q][0], acc, 0, 0, 0);
            acc = __builtin_amdgcn_mfma_f32_16x16x32_bf16(Ah1, Bh[q][1], acc, 0, 0, 0);
            acc = __builtin_amdgcn_mfma_f32_16x16x32_bf16(Al0, Bh[q][0], acc, 0, 0, 0);
            acc = __builtin_amdgcn_mfma_f32_16x16x32_bf16(Al1, Bh[q][1], acc, 0, 0, 0);
            acc = __builtin_amdgcn_mfma_f32_16x16x32_bf16(Ah0, Bl[q][0], acc, 0, 0, 0);
            acc = __builtin_amdgcn_mfma_f32_16x16x32_bf16(Ah1, Bl[q][1], acc, 0, 0, 0);
            float k0 = fmaf(2.f, acc[0], -x2v[0]);
            float k1 = fmaf(2.f, acc[1], -x2v[1]);
            float k2 = fmaf(2.f, acc[2], -x2v[2]);
            float k3 = fmaf(2.f, acc[3], -x2v[3]);
            int ln = q * 16 + (lane & 15);
            APPEND(k0, tau[q], ln, mbase + 0)
            APPEND(k1, tau[q], ln, mbase + 1)
            APPEND(k2, tau[q], ln, mbase + 2)
            APPEND(k3, tau[q], ln, mbase + 3)
        }
        Ah0 = nAh0; Al0 = nAl0; Ah1 = nAh1; Al1 = nAl1; x2v = nx2;
    }

    __syncthreads();
    // per-row top-12 of the packed keys (data is in LDS; 1 thread/row)
    if (threadIdx.x < 64) {
        int r = threadIdx.x;
        int c = cnt_s[r];
        size_t grow = (size_t)b * N_ + ng * 64 + r;
        cntg[grow] = c;
        int cc = min(c, CAP);
        unsigned best[12];                       // ascending; best[0] = smallest
#pragma unroll
        for (int j = 0; j < 12; ++j) best[j] = 0u;
        for (int s = 0; s < cc; ++s) {
            unsigned v = buf_s[r][s];
            if (v > best[0]) {
                best[0] = v;
#pragma unroll
                for (int j = 0; j < 11; ++j) {
                    bool sw = best[j] > best[j + 1];
                    unsigned t = best[j];
                    best[j]     = sw ? best[j + 1] : best[j];
                    best[j + 1] = sw ? t : best[j + 1];
                }
            }
        }
#pragma unroll
        for (int j = 0; j < 12; ++j)
            cand12[grow * 12 + j] = (unsigned short)(best[11 - j] & 0xFFFu);
    }
}

// exact fp64 re-rank of the 12 coarse-selected candidates -> true top-9.
// 2 rows per wave (half-wave each), 8 rows per block.
__global__ void k_refine(const float* __restrict__ xT, const unsigned short* __restrict__ cand12,
                         const int* __restrict__ cntg, int* __restrict__ idx9) {
    int wave = threadIdx.x >> 6, lane = threadIdx.x & 63;
    int half = lane >> 5, hl = lane & 31;
    int row = blockIdx.x * 8 + wave * 2 + half;
    int cnt = cntg[row];
    bool ok = (cnt >= KNN && cnt <= CAP);
    int cnt12 = min(cnt, 12);
    int b = row >> 12;

    double mykey = -1e300; int myidx = 0x7fffffff;
    if (ok && hl < cnt12) {
        int m = cand12[(size_t)row * 12 + hl];
        const float* xi = xT + (size_t)row * C_;
        const float* xm = xT + (((size_t)b << 12) + m) * C_;
        double d = 0.0, s2 = 0.0;
#pragma unroll
        for (int c4 = 0; c4 < 16; ++c4) {
            float4 a = *(const float4*)(xi + c4 * 4);
            float4 v = *(const float4*)(xm + c4 * 4);
            d = fma((double)a.x, (double)v.x, d);  s2 = fma((double)v.x, (double)v.x, s2);
            d = fma((double)a.y, (double)v.y, d);  s2 = fma((double)v.y, (double)v.y, s2);
            d = fma((double)a.z, (double)v.z, d);  s2 = fma((double)v.z, (double)v.z, s2);
            d = fma((double)a.w, (double)v.w, d);  s2 = fma((double)v.w, (double)v.w, s2);
        }
        mykey = 2.0 * d - s2;
        myidx = m;
    }
    for (int r = 0; r < KNN; ++r) {
        double k = mykey; int ix = myidx;
#pragma unroll
        for (int o = 16; o; o >>= 1) {           // half-wave butterfly
            double ok2 = __shfl_xor(k, o); int oi = __shfl_xor(ix, o);
            bool take = (ok2 > k) || (ok2 == k && oi < ix);
            k = take ? ok2 : k; ix = take ? oi : ix;
        }
        if (ok && hl == 0) idx9[(size_t)row * KNN + r] = ix;
        if (myidx == ix) { mykey = -1e300; myidx = 0x7fffffff; }  // unique per row
    }
}

// exact fp64 full scan for rows where the threshold buffer failed (insurance).
// One wave per row, early-exit; xi in registers; float4 loads; split fp64 chains.
__global__ void k_fallback(const float* __restrict__ xT, const int* __restrict__ cntg,
                           int* __restrict__ idx9) {
    int wave = threadIdx.x >> 6, lane = threadIdx.x & 63;
    int row = blockIdx.x * 4 + wave;            // grid 8192 * 4 waves = 32768 rows
    int cnt = cntg[row];
    if (cnt >= KNN && cnt <= CAP) return;
    int b = row >> 12;
    const float* xi = xT + (size_t)row * C_;
    float4 xr[16];
#pragma unroll
    for (int c4 = 0; c4 < 16; ++c4) xr[c4] = *(const float4*)(xi + c4 * 4);
    double sk[9]; int si[9];
#pragma unroll
    for (int j = 0; j < 9; ++j) { sk[j] = -1e300; si[j] = 0x7fffffff; }
    for (int mb = 0; mb < N_; mb += 64) {
        int m = mb + lane;
        const float* xm = xT + (((size_t)b << 12) + m) * C_;
        double d0 = 0.0, d1 = 0.0, s0 = 0.0, s1 = 0.0;
#pragma unroll
        for (int c4 = 0; c4 < 16; c4 += 2) {
            float4 v = *(const float4*)(xm + c4 * 4);
            float4 w = *(const float4*)(xm + c4 * 4 + 4);
            float4 a = xr[c4], bb = xr[c4 + 1];
            d0 = fma((double)a.x, (double)v.x, d0);  s0 = fma((double)v.x, (double)v.x, s0);
            d0 = fma((double)a.y, (double)v.y, d0);  s0 = fma((double)v.y, (double)v.y, s0);
            d0 = fma((double)a.z, (double)v.z, d0);  s0 = fma((double)v.z, (double)v.z, s0);
            d0 = fma((double)a.w, (double)v.w, d0);  s0 = fma((double)v.w, (double)v.w, s0);
            d1 = fma((double)bb.x, (double)w.x, d1); s1 = fma((double)w.x, (double)w.x, s1);
            d1 = fma((double)bb.y, (double)w.y, d1); s1 = fma((double)w.y, (double)w.y, s1);
            d1 = fma((double)bb.z, (double)w.z, d1); s1 = fma((double)w.z, (double)w.z, s1);
            d1 = fma((double)bb.w, (double)w.w, d1); s1 = fma((double)w.w, (double)w.w, s1);
        }
        double key = 2.0 * (d0 + d1) - (s0 + s1);
        if (key > sk[0] || (key == sk[0] && m < si[0])) {
            sk[0] = key; si[0] = m;
#pragma unroll
            for (int j = 0; j < 8; ++j) {
                bool sw = (sk[j] > sk[j + 1]) || (sk[j] == sk[j + 1] && si[j] < si[j + 1]);
                double tk = sk[j]; int ti = si[j];
                sk[j]     = sw ? sk[j + 1] : sk[j];
                si[j]     = sw ? si[j + 1] : si[j];
                sk[j + 1] = sw ? tk : sk[j + 1];
                si[j + 1] = sw ? ti : si[j + 1];
            }
        }
    }
    for (int r = 0; r < KNN; ++r) {
        double k = sk[8]; int ix = si[8];
#pragma unroll
        for (int o = 32; o; o >>= 1) {
            double ok = __shfl_xor(k, o); int oi = __shfl_xor(ix, o);
            bool take = (ok > k) || (ok == k && oi < ix);
            k = take ? ok : k; ix = take ? oi : ix;
        }
        if (lane == 0) idx9[(size_t)row * KNN + r] = ix;
        if (si[8] == ix) {
#pragma unroll
            for (int j = 8; j > 0; --j) { sk[j] = sk[j - 1]; si[j] = si[j - 1]; }
            sk[0] = -1e300; si[0] = 0x7fffffff;
        }
    }
}

// fused: gather-max (x_j - x_i) into LDS h-tile, then 1x1 conv + bias + ReLU
__global__ void k_gemm(const float* __restrict__ xT, const int* __restrict__ idx9,
                       const float* __restrict__ WT, const float* __restrict__ bias,
                       float* __restrict__ out) {
    __shared__ float h[64][129];
    int b  = blockIdx.x >> 6;
    int n0 = (blockIdx.x & 63) * 64;
    int wave = threadIdx.x >> 6, lane = threadIdx.x & 63;
    for (int r = 0; r < 16; ++r) {
        int nn = wave * 16 + r;
        size_t row = (size_t)b * N_ + n0 + nn;
        const int* id = idx9 + row * KNN;
        float m = -FLT_MAX;
#pragma unroll
        for (int k = 0; k < KNN; ++k) {
            int j = id[k];
            m = fmaxf(m, xT[(((size_t)b << 12) + j) * C_ + lane]);
        }
        float xic = xT[row * C_ + lane];
        h[nn][lane]      = xic;
        h[nn][64 + lane] = m - xic;
    }
    __syncthreads();
    int o0 = wave * 32;
    float acc[32];
#pragma unroll
    for (int j = 0; j < 32; ++j) acc[j] = 0.f;
    for (int c = 0; c < 2 * C_; ++c) {
        float hv = h[lane][c];
        const float4* wrow = (const float4*)(WT + (size_t)c * OUT_ + o0);
#pragma unroll
        for (int j4 = 0; j4 < 8; ++j4) {
            float4 w = wrow[j4];
            acc[j4 * 4 + 0] += w.x * hv;
            acc[j4 * 4 + 1] += w.y * hv;
            acc[j4 * 4 + 2] += w.z * hv;
            acc[j4 * 4 + 3] += w.w * hv;
        }
    }
#pragma unroll
    for (int j = 0; j < 32; ++j) {
        float v = acc[j] + bias[o0 + j];
        v = fmaxf(v, 0.f);
        out[((size_t)b * OUT_ + o0 + j) * N_ + n0 + lane] = v;
    }
}

extern "C" void kernel_launch(void* const* d_in, const int* in_sizes, int n_in,
                              void* d_out, int out_size, void* d_ws, size_t ws_size,
                              hipStream_t stream) {
    const float* x    = (const float*)d_in[0];
    const float* W    = (const float*)d_in[1];
    const float* bias = (const float*)d_in[2];
    float* out = (float*)d_out;
    char* ws = (char*)d_ws;

    float*          xT     = (float*)(ws);
    unsigned short* xfrag  = (unsigned short*)(ws + 8388608);
    int*            idx9   = (int*)(ws + 8388608);        // aliases xfrag (dead by refine)
    float*          x2     = (float*)(ws + 16777216);
    float*          WT     = (float*)(ws + 16908288);
    unsigned short* cand12 = (unsigned short*)(ws + 16973824);
    int*            cnt    = (int*)(ws + 17760256);

    k_wt       <<<dim3(64),   dim3(256), 0, stream>>>(W, WT);
    k_transpose<<<dim3(512),  dim3(256), 0, stream>>>(x, xT, x2, xfrag);
    k_topk_mf  <<<dim3(512),  dim3(256), 0, stream>>>(xfrag, x2, cand12, cnt);
    k_refine   <<<dim3(4096), dim3(256), 0, stream>>>(xT, cand12, cnt, idx9);
    k_fallback <<<dim3(8192), dim3(256), 0, stream>>>(xT, cnt, idx9);
    k_gemm     <<<dim3(512),  dim3(256), 0, stream>>>(xT, idx9, WT, bias, out);
}

// Round 9
// 187.033 us; speedup vs baseline: 3.1131x; 1.1703x over previous
//
#include <hip/hip_runtime.h>
#include <float.h>

#define B_   8
#define C_   64
#define N_   4096
#define OUT_ 128
#define KNN  9
#define CAP  128         // per-half append capacity (overflow -> exact fallback)
#define TAU_A 2.0f       // threshold: tau = TAU_A*sigma_n - 64

typedef __attribute__((ext_vector_type(8))) short short8;
typedef __attribute__((ext_vector_type(4))) float f32x4;

__device__ inline unsigned short f2bf(float f) {
    unsigned u = __float_as_uint(f);
    unsigned r = (u + 0x7fffu + ((u >> 16) & 1u)) >> 16;
    return (unsigned short)r;
}
__device__ inline float bf2f(unsigned short s) {
    return __uint_as_float(((unsigned)s) << 16);
}

// ---------------------------------------------------------------------------
// ws layout (bytes):
//   xT:     [B][N][C] float    @ 0          (8388608)
//   xfrag:  hi/lo bf16 chunks  @ 8388608    (8388608)  } idx9 aliases xfrag
//   idx9:   [B*N][9]  int      @ 8388608    (1179648)  } (xfrag dead by refine)
//   x2:     [B][N]    float    @ 16777216   (131072)
//   WT:     [2C][OUT] float    @ 16908288   (65536)
//   cand24: [B*N][24] u32      @ 16973824   (3145728)  packed (key20|idx12)
//   cnt2:   [B*N]     int2     @ 20119552   (262144)   total ~20.4 MB
// ---------------------------------------------------------------------------

__global__ void k_wt(const float* __restrict__ W, float* __restrict__ WT) {
    int e = blockIdx.x * 256 + threadIdx.x;
    int o = e >> 7, c = e & 127;
    WT[(size_t)c * OUT_ + o] = W[e];
}

// transpose + x2 + bf16 hi/lo fragment build (fused)
__global__ void k_transpose(const float* __restrict__ x, float* __restrict__ xT,
                            float* __restrict__ x2, unsigned short* __restrict__ xfrag) {
    __shared__ float t[C_][65];
    int b  = blockIdx.x & 7;                     // XCD-pinned batch
    int n0 = (blockIdx.x >> 3) * 64;
    int tid = threadIdx.x;
    for (int i = 0; i < 16; ++i) {
        int e = i * 256 + tid;
        int c = e >> 6, nn = e & 63;
        t[c][nn] = x[((size_t)b * C_ + c) * N_ + n0 + nn];
    }
    __syncthreads();
    for (int i = 0; i < 16; ++i) {
        int e = i * 256 + tid;
        int nn = e >> 6, c = e & 63;
        xT[((size_t)b * N_ + n0 + nn) * C_ + c] = t[c][nn];
    }
    int q = tid >> 6, L = tid & 63;
    int mloc = q * 16 + (L & 15);
    int k8 = (L >> 4) * 8;
    size_t cb = (size_t)(b * 256 + (n0 >> 4) + q) * 4 * 512;   // ushort units
#pragma unroll
    for (int h = 0; h < 2; ++h) {
        short8 hi, lo;
#pragma unroll
        for (int j = 0; j < 8; ++j) {
            float v = t[h * 32 + k8 + j][mloc];
            unsigned short hb = f2bf(v);
            float hf = bf2f(hb);
            unsigned short lb = f2bf(v - hf);
            hi[j] = (short)hb; lo[j] = (short)lb;
        }
        *(short8*)(xfrag + cb + (h * 2 + 0) * 512 + L * 8) = hi;
        *(short8*)(xfrag + cb + (h * 2 + 1) * 512 + L * 8) = lo;
    }
    if (tid < 64) {
        float s = 0.f;
        for (int c = 0; c < C_; ++c) { float v = t[c][tid]; s += v * v; }
        x2[(size_t)b * N_ + n0 + tid] = s;
    }
}

// append packed (20-bit sortable key | 12-bit index)
#define APPEND(KEY, TAU, LN, MIDX)                                      \
    if ((KEY) > (TAU)) {                                                \
        unsigned u = __float_as_uint(KEY);                              \
        u = (u & 0x80000000u) ? ~u : (u | 0x80000000u);                 \
        unsigned pk = (u & 0xFFFFF000u) | (unsigned)(MIDX);             \
        int sl = atomicAdd(&cnt_s[LN], 1);                              \
        if (sl < CAP) buf_s[LN][sl] = pk;                               \
    }

// MFMA scan + threshold compaction + in-LDS per-half top-12.
// grid 1024: b = blk&7 (XCD-pinned), mh = (blk>>3)&1 (m-half), ng = blk>>4.
// 64 n's/block; wave w scans m-tiles [mh*128 + w*32, +32) -> 32 iters.
__global__ __launch_bounds__(256, 4) void k_topk_mf(const unsigned short* __restrict__ xfrag,
                                                    const float* __restrict__ x2,
                                                    unsigned* __restrict__ cand24,
                                                    int* __restrict__ cnt2) {
    __shared__ int cnt_s[64];
    __shared__ unsigned buf_s[64][CAP];
    int b    = blockIdx.x & 7;
    int mh   = (blockIdx.x >> 3) & 1;
    int ng   = blockIdx.x >> 4;                  // 0..63
    int wave = threadIdx.x >> 6, lane = threadIdx.x & 63;
    if (threadIdx.x < 64) cnt_s[threadIdx.x] = 0;

    const short8* fr = (const short8*)xfrag;     // 16B units; chunk = 64 short8

    short8 Bh[4][2], Bl[4][2];
#pragma unroll
    for (int q = 0; q < 4; ++q)
#pragma unroll
        for (int h = 0; h < 2; ++h) {
            int ch = ((b * 256 + ng * 4 + q) * 4 + h * 2);
            Bh[q][h] = fr[(size_t)ch * 64 + lane];
            Bl[q][h] = fr[(size_t)(ch + 1) * 64 + lane];
        }

    float tau[4];
#pragma unroll
    for (int q = 0; q < 4; ++q) {
        float x2n = x2[b * N_ + ng * 64 + q * 16 + (lane & 15)];
        tau[q] = TAU_A * sqrtf(fmaf(4.f, x2n, 128.f)) - 64.f;
    }

    int mt0 = mh * 128 + wave * 32;              // m-tile start (32 tiles per wave)
    const short8* pA = fr + (size_t)(b * 256 + mt0) * 4 * 64 + lane;
    const f32x4*  px2 = (const f32x4*)(x2 + b * N_ + mt0 * 16 + (lane >> 4) * 4);
    short8 Ah0 = pA[0], Al0 = pA[64], Ah1 = pA[128], Al1 = pA[192];
    f32x4 x2v = *px2;

    __syncthreads();   // cnt_s zeroed

    for (int i = 0; i < 32; ++i) {
        if (i != 31) { pA += 256; px2 += 4; }
        short8 nAh0 = pA[0], nAl0 = pA[64], nAh1 = pA[128], nAl1 = pA[192];
        f32x4 nx2 = *px2;

        int mbase = (mt0 + i) * 16 + (lane >> 4) * 4;

#pragma unroll
        for (int q = 0; q < 4; ++q) {
            f32x4 acc = {0.f, 0.f, 0.f, 0.f};
            acc = __builtin_amdgcn_mfma_f32_16x16x32_bf16(Ah0, Bh[q][0], acc, 0, 0, 0);
            acc = __builtin_amdgcn_mfma_f32_16x16x32_bf16(Ah1, Bh[q][1], acc, 0, 0, 0);
            acc = __builtin_amdgcn_mfma_f32_16x16x32_bf16(Al0, Bh[q][0], acc, 0, 0, 0);
            acc = __builtin_amdgcn_mfma_f32_16x16x32_bf16(Al1, Bh[q][1], acc, 0, 0, 0);
            acc = __builtin_amdgcn_mfma_f32_16x16x32_bf16(Ah0, Bl[q][0], acc, 0, 0, 0);
            acc = __builtin_amdgcn_mfma_f32_16x16x32_bf16(Ah1, Bl[q][1], acc, 0, 0, 0);
            float k0 = fmaf(2.f, acc[0], -x2v[0]);
            float k1 = fmaf(2.f, acc[1], -x2v[1]);
            float k2 = fmaf(2.f, acc[2], -x2v[2]);
            float k3 = fmaf(2.f, acc[3], -x2v[3]);
            int ln = q * 16 + (lane & 15);
            APPEND(k0, tau[q], ln, mbase + 0)
            APPEND(k1, tau[q], ln, mbase + 1)
            APPEND(k2, tau[q], ln, mbase + 2)
            APPEND(k3, tau[q], ln, mbase + 3)
        }
        Ah0 = nAh0; Al0 = nAl0; Ah1 = nAh1; Al1 = nAl1; x2v = nx2;
    }

    __syncthreads();
    // per-row top-12 of this half's packed keys (1 thread/row)
    if (threadIdx.x < 64) {
        int r = threadIdx.x;
        int c = cnt_s[r];
        size_t grow = (size_t)b * N_ + ng * 64 + r;
        cnt2[grow * 2 + mh] = c;
        int cc = min(c, CAP);
        unsigned best[12];                       // ascending; best[0] = smallest
#pragma unroll
        for (int j = 0; j < 12; ++j) best[j] = 0u;
        for (int s = 0; s < cc; ++s) {
            unsigned v = buf_s[r][s];
            if (v > best[0]) {
                best[0] = v;
#pragma unroll
                for (int j = 0; j < 11; ++j) {
                    bool sw = best[j] > best[j + 1];
                    unsigned t = best[j];
                    best[j]     = sw ? best[j + 1] : best[j];
                    best[j + 1] = sw ? t : best[j + 1];
                }
            }
        }
#pragma unroll
        for (int j = 0; j < 12; ++j)
            cand24[grow * 24 + mh * 12 + j] = best[11 - j];
    }
}

// exact fp64 re-rank of up to 24 coarse candidates -> true top-9.
// 2 rows per wave (half-wave each); XCD-pinned to batch for L2 locality.
__global__ void k_refine(const float* __restrict__ xT, const unsigned* __restrict__ cand24,
                         const int* __restrict__ cnt2, int* __restrict__ idx9) {
    int wave = threadIdx.x >> 6, lane = threadIdx.x & 63;
    int half = lane >> 5, hl = lane & 31;
    int b = blockIdx.x & 7;
    int row = b * N_ + (blockIdx.x >> 3) * 8 + wave * 2 + half;
    int c0 = cnt2[(size_t)row * 2 + 0];
    int c1 = cnt2[(size_t)row * 2 + 1];
    bool ok = (c0 + c1 >= KNN) && (c0 <= CAP) && (c1 <= CAP);
    int c0c = min(c0, 12), c1c = min(c1, 12);

    double mykey = -1e300; int myidx = 0x7fffffff;
    bool valid = ok && ((hl < 12) ? (hl < c0c) : (hl < 24 && (hl - 12) < c1c));
    if (valid) {
        int m = (int)(cand24[(size_t)row * 24 + hl] & 0xFFFu);
        const float* xi = xT + (size_t)row * C_;
        const float* xm = xT + (((size_t)b << 12) + m) * C_;
        double d = 0.0, s2 = 0.0;
#pragma unroll
        for (int c4 = 0; c4 < 16; ++c4) {
            float4 a = *(const float4*)(xi + c4 * 4);
            float4 v = *(const float4*)(xm + c4 * 4);
            d = fma((double)a.x, (double)v.x, d);  s2 = fma((double)v.x, (double)v.x, s2);
            d = fma((double)a.y, (double)v.y, d);  s2 = fma((double)v.y, (double)v.y, s2);
            d = fma((double)a.z, (double)v.z, d);  s2 = fma((double)v.z, (double)v.z, s2);
            d = fma((double)a.w, (double)v.w, d);  s2 = fma((double)v.w, (double)v.w, s2);
        }
        mykey = 2.0 * d - s2;
        myidx = m;
    }
    for (int r = 0; r < KNN; ++r) {
        double k = mykey; int ix = myidx;
#pragma unroll
        for (int o = 16; o; o >>= 1) {           // half-wave butterfly
            double ok2 = __shfl_xor(k, o); int oi = __shfl_xor(ix, o);
            bool take = (ok2 > k) || (ok2 == k && oi < ix);
            k = take ? ok2 : k; ix = take ? oi : ix;
        }
        if (ok && hl == 0) idx9[(size_t)row * KNN + r] = ix;
        if (myidx == ix) { mykey = -1e300; myidx = 0x7fffffff; }  // unique per row
    }
}

// exact fp64 full scan for rows where the threshold buffers failed (insurance).
__global__ void k_fallback(const float* __restrict__ xT, const int* __restrict__ cnt2,
                           int* __restrict__ idx9) {
    int wave = threadIdx.x >> 6, lane = threadIdx.x & 63;
    int row = blockIdx.x * 4 + wave;            // 8192 blocks * 4 waves = 32768 rows
    int c0 = cnt2[(size_t)row * 2 + 0];
    int c1 = cnt2[(size_t)row * 2 + 1];
    if ((c0 + c1 >= KNN) && (c0 <= CAP) && (c1 <= CAP)) return;
    int b = row >> 12;
    const float* xi = xT + (size_t)row * C_;
    float4 xr[16];
#pragma unroll
    for (int c4 = 0; c4 < 16; ++c4) xr[c4] = *(const float4*)(xi + c4 * 4);
    double sk[9]; int si[9];
#pragma unroll
    for (int j = 0; j < 9; ++j) { sk[j] = -1e300; si[j] = 0x7fffffff; }
    for (int mb = 0; mb < N_; mb += 64) {
        int m = mb + lane;
        const float* xm = xT + (((size_t)b << 12) + m) * C_;
        double d0 = 0.0, d1 = 0.0, s0 = 0.0, s1 = 0.0;
#pragma unroll
        for (int c4 = 0; c4 < 16; c4 += 2) {
            float4 v = *(const float4*)(xm + c4 * 4);
            float4 w = *(const float4*)(xm + c4 * 4 + 4);
            float4 a = xr[c4], bb = xr[c4 + 1];
            d0 = fma((double)a.x, (double)v.x, d0);  s0 = fma((double)v.x, (double)v.x, s0);
            d0 = fma((double)a.y, (double)v.y, d0);  s0 = fma((double)v.y, (double)v.y, s0);
            d0 = fma((double)a.z, (double)v.z, d0);  s0 = fma((double)v.z, (double)v.z, s0);
            d0 = fma((double)a.w, (double)v.w, d0);  s0 = fma((double)v.w, (double)v.w, s0);
            d1 = fma((double)bb.x, (double)w.x, d1); s1 = fma((double)w.x, (double)w.x, s1);
            d1 = fma((double)bb.y, (double)w.y, d1); s1 = fma((double)w.y, (double)w.y, s1);
            d1 = fma((double)bb.z, (double)w.z, d1); s1 = fma((double)w.z, (double)w.z, s1);
            d1 = fma((double)bb.w, (double)w.w, d1); s1 = fma((double)w.w, (double)w.w, s1);
        }
        double key = 2.0 * (d0 + d1) - (s0 + s1);
        if (key > sk[0] || (key == sk[0] && m < si[0])) {
            sk[0] = key; si[0] = m;
#pragma unroll
            for (int j = 0; j < 8; ++j) {
                bool sw = (sk[j] > sk[j + 1]) || (sk[j] == sk[j + 1] && si[j] < si[j + 1]);
                double tk = sk[j]; int ti = si[j];
                sk[j]     = sw ? sk[j + 1] : sk[j];
                si[j]     = sw ? si[j + 1] : si[j];
                sk[j + 1] = sw ? tk : sk[j + 1];
                si[j + 1] = sw ? ti : si[j + 1];
            }
        }
    }
    for (int r = 0; r < KNN; ++r) {
        double k = sk[8]; int ix = si[8];
#pragma unroll
        for (int o = 32; o; o >>= 1) {
            double ok = __shfl_xor(k, o); int oi = __shfl_xor(ix, o);
            bool take = (ok > k) || (ok == k && oi < ix);
            k = take ? ok : k; ix = take ? oi : ix;
        }
        if (lane == 0) idx9[(size_t)row * KNN + r] = ix;
        if (si[8] == ix) {
#pragma unroll
            for (int j = 8; j > 0; --j) { sk[j] = sk[j - 1]; si[j] = si[j - 1]; }
            sk[0] = -1e300; si[0] = 0x7fffffff;
        }
    }
}

// fused: gather-max (x_j - x_i) into LDS h-tile, then 1x1 conv + bias + ReLU
__global__ void k_gemm(const float* __restrict__ xT, const int* __restrict__ idx9,
                       const float* __restrict__ WT, const float* __restrict__ bias,
                       float* __restrict__ out) {
    __shared__ float h[64][129];
    int b  = blockIdx.x & 7;                     // XCD-pinned batch
    int n0 = (blockIdx.x >> 3) * 64;
    int wave = threadIdx.x >> 6, lane = threadIdx.x & 63;
    for (int r = 0; r < 16; ++r) {
        int nn = wave * 16 + r;
        size_t row = (size_t)b * N_ + n0 + nn;
        const int* id = idx9 + row * KNN;
        float m = -FLT_MAX;
#pragma unroll
        for (int k = 0; k < KNN; ++k) {
            int j = id[k];
            m = fmaxf(m, xT[(((size_t)b << 12) + j) * C_ + lane]);
        }
        float xic = xT[row * C_ + lane];
        h[nn][lane]      = xic;
        h[nn][64 + lane] = m - xic;
    }
    __syncthreads();
    int o0 = wave * 32;
    float acc[32];
#pragma unroll
    for (int j = 0; j < 32; ++j) acc[j] = 0.f;
    for (int c = 0; c < 2 * C_; ++c) {
        float hv = h[lane][c];
        const float4* wrow = (const float4*)(WT + (size_t)c * OUT_ + o0);
#pragma unroll
        for (int j4 = 0; j4 < 8; ++j4) {
            float4 w = wrow[j4];
            acc[j4 * 4 + 0] += w.x * hv;
            acc[j4 * 4 + 1] += w.y * hv;
            acc[j4 * 4 + 2] += w.z * hv;
            acc[j4 * 4 + 3] += w.w * hv;
        }
    }
#pragma unroll
    for (int j = 0; j < 32; ++j) {
        float v = acc[j] + bias[o0 + j];
        v = fmaxf(v, 0.f);
        out[((size_t)b * OUT_ + o0 + j) * N_ + n0 + lane] = v;
    }
}

extern "C" void kernel_launch(void* const* d_in, const int* in_sizes, int n_in,
                              void* d_out, int out_size, void* d_ws, size_t ws_size,
                              hipStream_t stream) {
    const float* x    = (const float*)d_in[0];
    const float* W    = (const float*)d_in[1];
    const float* bias = (const float*)d_in[2];
    float* out = (float*)d_out;
    char* ws = (char*)d_ws;

    float*          xT     = (float*)(ws);
    unsigned short* xfrag  = (unsigned short*)(ws + 8388608);
    int*            idx9   = (int*)(ws + 8388608);        // aliases xfrag (dead by refine)
    float*          x2     = (float*)(ws + 16777216);
    float*          WT     = (float*)(ws + 16908288);
    unsigned*       cand24 = (unsigned*)(ws + 16973824);
    int*            cnt2   = (int*)(ws + 20119552);

    k_wt       <<<dim3(64),   dim3(256), 0, stream>>>(W, WT);
    k_transpose<<<dim3(512),  dim3(256), 0, stream>>>(x, xT, x2, xfrag);
    k_topk_mf  <<<dim3(1024), dim3(256), 0, stream>>>(xfrag, x2, cand24, cnt2);
    k_refine   <<<dim3(4096), dim3(256), 0, stream>>>(xT, cand24, cnt2, idx9);
    k_fallback <<<dim3(8192), dim3(256), 0, stream>>>(xT, cnt2, idx9);
    k_gemm     <<<dim3(512),  dim3(256), 0, stream>>>(xT, idx9, WT, bias, out);
}

// Round 10
// 168.835 us; speedup vs baseline: 3.4487x; 1.1078x over previous
//
#include <hip/hip_runtime.h>
#include <float.h>

#define B_   8
#define C_   64
#define N_   4096
#define OUT_ 128
#define KNN  9
#define CAP  64          // per-half append capacity (overflow -> exact fallback)
#define TAU_A 2.15f      // threshold: tau = TAU_A*sigma_n - 64

typedef __attribute__((ext_vector_type(8))) short short8;
typedef __attribute__((ext_vector_type(4))) float f32x4;

__device__ inline unsigned short f2bf(float f) {
    unsigned u = __float_as_uint(f);
    unsigned r = (u + 0x7fffu + ((u >> 16) & 1u)) >> 16;
    return (unsigned short)r;
}

// ---------------------------------------------------------------------------
// ws layout (bytes):
//   xT:     [B][N][C] float    @ 0          (8388608)
//   xfrag:  hi bf16 chunks     @ 8388608    (4194304)  } idx9 aliases xfrag
//   idx9:   [B*N][9]  int      @ 8388608    (1179648)  } (xfrag dead by refine)
//   x2:     [B][N]    float    @ 16777216   (131072)
//   WT:     [2C][OUT] float    @ 16908288   (65536)
//   cand24: [B*N][24] u32      @ 16973824   (3145728)  packed (key20|idx12)
//   cnt2:   [B*N]     int2     @ 20119552   (262144)   total ~20.4 MB
//
// xfrag: per (b, m-tile t, khalf h) one 1KB chunk at ((b*256+t)*2+h)*1024;
// lane L holds 8 bf16 = x[b][m=t*16+(L&15)][k=h*32+(L>>4)*8 .. +7].
// bf16-hi ONLY: key error sigma ~0.09 << rank9->rank13 key gap (~3.6);
// exact fp64 refine/fallback make final selection bit-exact regardless.
// ---------------------------------------------------------------------------

__global__ void k_wt(const float* __restrict__ W, float* __restrict__ WT) {
    int e = blockIdx.x * 256 + threadIdx.x;
    int o = e >> 7, c = e & 127;
    WT[(size_t)c * OUT_ + o] = W[e];
}

// transpose + x2 + bf16-hi fragment build (fused)
__global__ void k_transpose(const float* __restrict__ x, float* __restrict__ xT,
                            float* __restrict__ x2, unsigned short* __restrict__ xfrag) {
    __shared__ float t[C_][65];
    int b  = blockIdx.x & 7;                     // XCD-pinned batch
    int n0 = (blockIdx.x >> 3) * 64;
    int tid = threadIdx.x;
    for (int i = 0; i < 16; ++i) {
        int e = i * 256 + tid;
        int c = e >> 6, nn = e & 63;
        t[c][nn] = x[((size_t)b * C_ + c) * N_ + n0 + nn];
    }
    __syncthreads();
    for (int i = 0; i < 16; ++i) {
        int e = i * 256 + tid;
        int nn = e >> 6, c = e & 63;
        xT[((size_t)b * N_ + n0 + nn) * C_ + c] = t[c][nn];
    }
    int q = tid >> 6, L = tid & 63;
    int mloc = q * 16 + (L & 15);
    int k8 = (L >> 4) * 8;
    size_t cb = (size_t)(b * 256 + (n0 >> 4) + q) * 2 * 512;   // ushort units
#pragma unroll
    for (int h = 0; h < 2; ++h) {
        short8 hi;
#pragma unroll
        for (int j = 0; j < 8; ++j)
            hi[j] = (short)f2bf(t[h * 32 + k8 + j][mloc]);
        *(short8*)(xfrag + cb + h * 512 + L * 8) = hi;
    }
    if (tid < 64) {
        float s = 0.f;
        for (int c = 0; c < C_; ++c) { float v = t[c][tid]; s += v * v; }
        x2[(size_t)b * N_ + n0 + tid] = s;
    }
}

// append packed (20-bit sortable key | 12-bit index)
#define APPEND(KEY, TAU, LN, MIDX)                                      \
    if ((KEY) > (TAU)) {                                                \
        unsigned u = __float_as_uint(KEY);                              \
        u = (u & 0x80000000u) ? ~u : (u | 0x80000000u);                 \
        unsigned pk = (u & 0xFFFFF000u) | (unsigned)(MIDX);             \
        int sl = atomicAdd(&cnt_s[LN], 1);                              \
        if (sl < CAP) buf_s[LN][sl] = pk;                               \
    }

// MFMA scan (bf16-hi) + threshold compaction + in-LDS per-half top-12.
// grid 1024: b = blk&7 (XCD-pinned), mh = (blk>>3)&1, ng = blk>>4.
// 64 n's/block; wave w scans m-tiles [mh*128 + w*32, +32).
__global__ __launch_bounds__(256, 4) void k_topk_mf(const unsigned short* __restrict__ xfrag,
                                                    const float* __restrict__ x2,
                                                    unsigned* __restrict__ cand24,
                                                    int* __restrict__ cnt2) {
    __shared__ int cnt_s[64];
    __shared__ unsigned buf_s[64][CAP];
    int b    = blockIdx.x & 7;
    int mh   = (blockIdx.x >> 3) & 1;
    int ng   = blockIdx.x >> 4;                  // 0..63
    int wave = threadIdx.x >> 6, lane = threadIdx.x & 63;
    if (threadIdx.x < 64) cnt_s[threadIdx.x] = 0;

    const short8* fr = (const short8*)xfrag;     // 16B units; chunk = 64 short8

    short8 Bh[4][2];
#pragma unroll
    for (int q = 0; q < 4; ++q)
#pragma unroll
        for (int h = 0; h < 2; ++h) {
            int ch = ((b * 256 + ng * 4 + q) * 2 + h);
            Bh[q][h] = fr[(size_t)ch * 64 + lane];
        }

    float tau[4];
#pragma unroll
    for (int q = 0; q < 4; ++q) {
        float x2n = x2[b * N_ + ng * 64 + q * 16 + (lane & 15)];
        tau[q] = TAU_A * sqrtf(fmaf(4.f, x2n, 128.f)) - 64.f;
    }

    int mt0 = mh * 128 + wave * 32;              // m-tile start (32 tiles per wave)
    const short8* pA = fr + (size_t)(b * 256 + mt0) * 2 * 64 + lane;
    const f32x4*  px2 = (const f32x4*)(x2 + b * N_ + mt0 * 16 + (lane >> 4) * 4);
    short8 Ah0 = pA[0], Ah1 = pA[64];
    f32x4 x2v = *px2;

    __syncthreads();   // cnt_s zeroed

    for (int i = 0; i < 32; ++i) {
        if (i != 31) { pA += 128; px2 += 4; }
        short8 nAh0 = pA[0], nAh1 = pA[64];
        f32x4 nx2 = *px2;

        int mbase = (mt0 + i) * 16 + (lane >> 4) * 4;

#pragma unroll
        for (int q = 0; q < 4; ++q) {
            f32x4 acc = {0.f, 0.f, 0.f, 0.f};
            acc = __builtin_amdgcn_mfma_f32_16x16x32_bf16(Ah0, Bh[q][0], acc, 0, 0, 0);
            acc = __builtin_amdgcn_mfma_f32_16x16x32_bf16(Ah1, Bh[q][1], acc, 0, 0, 0);
            float k0 = fmaf(2.f, acc[0], -x2v[0]);
            float k1 = fmaf(2.f, acc[1], -x2v[1]);
            float k2 = fmaf(2.f, acc[2], -x2v[2]);
            float k3 = fmaf(2.f, acc[3], -x2v[3]);
            int ln = q * 16 + (lane & 15);
            APPEND(k0, tau[q], ln, mbase + 0)
            APPEND(k1, tau[q], ln, mbase + 1)
            APPEND(k2, tau[q], ln, mbase + 2)
            APPEND(k3, tau[q], ln, mbase + 3)
        }
        Ah0 = nAh0; Ah1 = nAh1; x2v = nx2;
    }

    __syncthreads();
    // per-row top-12 of this half's packed keys (1 thread/row)
    if (threadIdx.x < 64) {
        int r = threadIdx.x;
        int c = cnt_s[r];
        size_t grow = (size_t)b * N_ + ng * 64 + r;
        cnt2[grow * 2 + mh] = c;
        int cc = min(c, CAP);
        unsigned best[12];                       // ascending; best[0] = smallest
#pragma unroll
        for (int j = 0; j < 12; ++j) best[j] = 0u;
        for (int s = 0; s < cc; ++s) {
            unsigned v = buf_s[r][s];
            if (v > best[0]) {
                best[0] = v;
#pragma unroll
                for (int j = 0; j < 11; ++j) {
                    bool sw = best[j] > best[j + 1];
                    unsigned t = best[j];
                    best[j]     = sw ? best[j + 1] : best[j];
                    best[j + 1] = sw ? t : best[j + 1];
                }
            }
        }
#pragma unroll
        for (int j = 0; j < 12; ++j)
            cand24[grow * 24 + mh * 12 + j] = best[11 - j];
    }
}

// exact fp64 re-rank of up to 24 coarse candidates -> true top-9.
// 2 rows per wave (half-wave each); XCD-pinned to batch for L2 locality.
__global__ void k_refine(const float* __restrict__ xT, const unsigned* __restrict__ cand24,
                         const int* __restrict__ cnt2, int* __restrict__ idx9) {
    int wave = threadIdx.x >> 6, lane = threadIdx.x & 63;
    int half = lane >> 5, hl = lane & 31;
    int b = blockIdx.x & 7;
    int row = b * N_ + (blockIdx.x >> 3) * 8 + wave * 2 + half;
    int c0 = cnt2[(size_t)row * 2 + 0];
    int c1 = cnt2[(size_t)row * 2 + 1];
    bool ok = (c0 + c1 >= KNN) && (c0 <= CAP) && (c1 <= CAP);
    int c0c = min(c0, 12), c1c = min(c1, 12);

    double mykey = -1e300; int myidx = 0x7fffffff;
    bool valid = ok && ((hl < 12) ? (hl < c0c) : (hl < 24 && (hl - 12) < c1c));
    if (valid) {
        int m = (int)(cand24[(size_t)row * 24 + hl] & 0xFFFu);
        const float* xi = xT + (size_t)row * C_;
        const float* xm = xT + (((size_t)b << 12) + m) * C_;
        double d = 0.0, s2 = 0.0;
#pragma unroll
        for (int c4 = 0; c4 < 16; ++c4) {
            float4 a = *(const float4*)(xi + c4 * 4);
            float4 v = *(const float4*)(xm + c4 * 4);
            d = fma((double)a.x, (double)v.x, d);  s2 = fma((double)v.x, (double)v.x, s2);
            d = fma((double)a.y, (double)v.y, d);  s2 = fma((double)v.y, (double)v.y, s2);
            d = fma((double)a.z, (double)v.z, d);  s2 = fma((double)v.z, (double)v.z, s2);
            d = fma((double)a.w, (double)v.w, d);  s2 = fma((double)v.w, (double)v.w, s2);
        }
        mykey = 2.0 * d - s2;
        myidx = m;
    }
    for (int r = 0; r < KNN; ++r) {
        double k = mykey; int ix = myidx;
#pragma unroll
        for (int o = 16; o; o >>= 1) {           // half-wave butterfly
            double ok2 = __shfl_xor(k, o); int oi = __shfl_xor(ix, o);
            bool take = (ok2 > k) || (ok2 == k && oi < ix);
            k = take ? ok2 : k; ix = take ? oi : ix;
        }
        if (ok && hl == 0) idx9[(size_t)row * KNN + r] = ix;
        if (myidx == ix) { mykey = -1e300; myidx = 0x7fffffff; }  // unique per row
    }
}

// exact fp64 full scan for rows where the threshold buffers failed (insurance).
__global__ void k_fallback(const float* __restrict__ xT, const int* __restrict__ cnt2,
                           int* __restrict__ idx9) {
    int wave = threadIdx.x >> 6, lane = threadIdx.x & 63;
    int row = blockIdx.x * 4 + wave;            // 8192 blocks * 4 waves = 32768 rows
    int c0 = cnt2[(size_t)row * 2 + 0];
    int c1 = cnt2[(size_t)row * 2 + 1];
    if ((c0 + c1 >= KNN) && (c0 <= CAP) && (c1 <= CAP)) return;
    int b = row >> 12;
    const float* xi = xT + (size_t)row * C_;
    float4 xr[16];
#pragma unroll
    for (int c4 = 0; c4 < 16; ++c4) xr[c4] = *(const float4*)(xi + c4 * 4);
    double sk[9]; int si[9];
#pragma unroll
    for (int j = 0; j < 9; ++j) { sk[j] = -1e300; si[j] = 0x7fffffff; }
    for (int mb = 0; mb < N_; mb += 64) {
        int m = mb + lane;
        const float* xm = xT + (((size_t)b << 12) + m) * C_;
        double d0 = 0.0, d1 = 0.0, s0 = 0.0, s1 = 0.0;
#pragma unroll
        for (int c4 = 0; c4 < 16; c4 += 2) {
            float4 v = *(const float4*)(xm + c4 * 4);
            float4 w = *(const float4*)(xm + c4 * 4 + 4);
            float4 a = xr[c4], bb = xr[c4 + 1];
            d0 = fma((double)a.x, (double)v.x, d0);  s0 = fma((double)v.x, (double)v.x, s0);
            d0 = fma((double)a.y, (double)v.y, d0);  s0 = fma((double)v.y, (double)v.y, s0);
            d0 = fma((double)a.z, (double)v.z, d0);  s0 = fma((double)v.z, (double)v.z, s0);
            d0 = fma((double)a.w, (double)v.w, d0);  s0 = fma((double)v.w, (double)v.w, s0);
            d1 = fma((double)bb.x, (double)w.x, d1); s1 = fma((double)w.x, (double)w.x, s1);
            d1 = fma((double)bb.y, (double)w.y, d1); s1 = fma((double)w.y, (double)w.y, s1);
            d1 = fma((double)bb.z, (double)w.z, d1); s1 = fma((double)w.z, (double)w.z, s1);
            d1 = fma((double)bb.w, (double)w.w, d1); s1 = fma((double)w.w, (double)w.w, s1);
        }
        double key = 2.0 * (d0 + d1) - (s0 + s1);
        if (key > sk[0] || (key == sk[0] && m < si[0])) {
            sk[0] = key; si[0] = m;
#pragma unroll
            for (int j = 0; j < 8; ++j) {
                bool sw = (sk[j] > sk[j + 1]) || (sk[j] == sk[j + 1] && si[j] < si[j + 1]);
                double tk = sk[j]; int ti = si[j];
                sk[j]     = sw ? sk[j + 1] : sk[j];
                si[j]     = sw ? si[j + 1] : si[j];
                sk[j + 1] = sw ? tk : sk[j + 1];
                si[j + 1] = sw ? ti : si[j + 1];
            }
        }
    }
    for (int r = 0; r < KNN; ++r) {
        double k = sk[8]; int ix = si[8];
#pragma unroll
        for (int o = 32; o; o >>= 1) {
            double ok = __shfl_xor(k, o); int oi = __shfl_xor(ix, o);
            bool take = (ok > k) || (ok == k && oi < ix);
            k = take ? ok : k; ix = take ? oi : ix;
        }
        if (lane == 0) idx9[(size_t)row * KNN + r] = ix;
        if (si[8] == ix) {
#pragma unroll
            for (int j = 8; j > 0; --j) { sk[j] = sk[j - 1]; si[j] = si[j - 1]; }
            sk[0] = -1e300; si[0] = 0x7fffffff;
        }
    }
}

// fused: gather-max (x_j - x_i) into LDS h-tile, then 1x1 conv + bias + ReLU
__global__ void k_gemm(const float* __restrict__ xT, const int* __restrict__ idx9,
                       const float* __restrict__ WT, const float* __restrict__ bias,
                       float* __restrict__ out) {
    __shared__ float h[64][129];
    int b  = blockIdx.x & 7;                     // XCD-pinned batch
    int n0 = (blockIdx.x >> 3) * 64;
    int wave = threadIdx.x >> 6, lane = threadIdx.x & 63;
    for (int r = 0; r < 16; ++r) {
        int nn = wave * 16 + r;
        size_t row = (size_t)b * N_ + n0 + nn;
        const int* id = idx9 + row * KNN;
        float m = -FLT_MAX;
#pragma unroll
        for (int k = 0; k < KNN; ++k) {
            int j = id[k];
            m = fmaxf(m, xT[(((size_t)b << 12) + j) * C_ + lane]);
        }
        float xic = xT[row * C_ + lane];
        h[nn][lane]      = xic;
        h[nn][64 + lane] = m - xic;
    }
    __syncthreads();
    int o0 = wave * 32;
    float acc[32];
#pragma unroll
    for (int j = 0; j < 32; ++j) acc[j] = 0.f;
    for (int c = 0; c < 2 * C_; ++c) {
        float hv = h[lane][c];
        const float4* wrow = (const float4*)(WT + (size_t)c * OUT_ + o0);
#pragma unroll
        for (int j4 = 0; j4 < 8; ++j4) {
            float4 w = wrow[j4];
            acc[j4 * 4 + 0] += w.x * hv;
            acc[j4 * 4 + 1] += w.y * hv;
            acc[j4 * 4 + 2] += w.z * hv;
            acc[j4 * 4 + 3] += w.w * hv;
        }
    }
#pragma unroll
    for (int j = 0; j < 32; ++j) {
        float v = acc[j] + bias[o0 + j];
        v = fmaxf(v, 0.f);
        out[((size_t)b * OUT_ + o0 + j) * N_ + n0 + lane] = v;
    }
}

extern "C" void kernel_launch(void* const* d_in, const int* in_sizes, int n_in,
                              void* d_out, int out_size, void* d_ws, size_t ws_size,
                              hipStream_t stream) {
    const float* x    = (const float*)d_in[0];
    const float* W    = (const float*)d_in[1];
    const float* bias = (const float*)d_in[2];
    float* out = (float*)d_out;
    char* ws = (char*)d_ws;

    float*          xT     = (float*)(ws);
    unsigned short* xfrag  = (unsigned short*)(ws + 8388608);
    int*            idx9   = (int*)(ws + 8388608);        // aliases xfrag (dead by refine)
    float*          x2     = (float*)(ws + 16777216);
    float*          WT     = (float*)(ws + 16908288);
    unsigned*       cand24 = (unsigned*)(ws + 16973824);
    int*            cnt2   = (int*)(ws + 20119552);

    k_wt       <<<dim3(64),   dim3(256), 0, stream>>>(W, WT);
    k_transpose<<<dim3(512),  dim3(256), 0, stream>>>(x, xT, x2, xfrag);
    k_topk_mf  <<<dim3(1024), dim3(256), 0, stream>>>(xfrag, x2, cand24, cnt2);
    k_refine   <<<dim3(4096), dim3(256), 0, stream>>>(xT, cand24, cnt2, idx9);
    k_fallback <<<dim3(8192), dim3(256), 0, stream>>>(xT, cnt2, idx9);
    k_gemm     <<<dim3(512),  dim3(256), 0, stream>>>(xT, idx9, WT, bias, out);
}

// Round 11
// 116.852 us; speedup vs baseline: 4.9829x; 1.4449x over previous
//
#include <hip/hip_runtime.h>
#include <float.h>

#define B_   8
#define C_   64
#define N_   4096
#define OUT_ 128
#define KNN  9
#define CAP  64          // per-half append capacity (overflow -> exact fallback)
#define TAU_A 2.15f      // threshold: tau = TAU_A*sigma_n - 64

typedef __attribute__((ext_vector_type(8))) short short8;
typedef __attribute__((ext_vector_type(4))) float f32x4;

__device__ inline unsigned short f2bf(float f) {
    unsigned u = __float_as_uint(f);
    unsigned r = (u + 0x7fffu + ((u >> 16) & 1u)) >> 16;
    return (unsigned short)r;
}
__device__ inline float bf2f(unsigned short s) {
    return __uint_as_float(((unsigned)s) << 16);
}

// ---------------------------------------------------------------------------
// ws layout (bytes):
//   xT:     [B][N][C] float    @ 0          (8388608)
//   xfrag:  hi bf16 chunks     @ 8388608    (4194304)  } idx9 aliases xfrag
//   idx9:   [B*N][9]  int      @ 8388608    (1179648)  } (xfrag dead by refine)
//   x2:     [B][N]    float    @ 16777216   (131072)
//   wfrag:  W hi/lo bf16 frags @ 16908288   (65536)
//   cand24: [B*N][24] u32      @ 16973824   (3145728)  packed (key20|idx12)
//   cnt2:   [B*N]     int2     @ 20119552   (262144)   total ~20.4 MB
//
// frag chunk convention (1KB, proven by k_topk_mf): lane L holds 8 bf16 =
// M[row = tile*16 + (L&15)][k = kc*32 + (L>>4)*8 .. +7].
// ---------------------------------------------------------------------------

// W -> hi/lo fragment chunks. grid 8 (o-tile), wave = kc, lane = chunk slot.
__global__ void k_wt(const float* __restrict__ W, unsigned short* __restrict__ wfrag) {
    int mt = blockIdx.x, kc = threadIdx.x >> 6, L = threadIdx.x & 63;
    int o  = mt * 16 + (L & 15);
    int c0 = kc * 32 + ((L >> 4) * 8);
    const float* src = W + (size_t)o * 128 + c0;
    float4 v0 = *(const float4*)src, v1 = *(const float4*)(src + 4);
    float vs[8] = {v0.x, v0.y, v0.z, v0.w, v1.x, v1.y, v1.z, v1.w};
    short8 hi, lo;
#pragma unroll
    for (int j = 0; j < 8; ++j) {
        unsigned short hb = f2bf(vs[j]);
        float hf = bf2f(hb);
        lo[j] = (short)f2bf(vs[j] - hf);
        hi[j] = (short)hb;
    }
    size_t cb = (size_t)(mt * 4 + kc) * 2 * 512;   // ushort units
    *(short8*)(wfrag + cb + L * 8)       = hi;
    *(short8*)(wfrag + cb + 512 + L * 8) = lo;
}

// transpose + x2 + bf16-hi fragment build (fused)
__global__ void k_transpose(const float* __restrict__ x, float* __restrict__ xT,
                            float* __restrict__ x2, unsigned short* __restrict__ xfrag) {
    __shared__ float t[C_][65];
    int b  = blockIdx.x & 7;                     // XCD-pinned batch
    int n0 = (blockIdx.x >> 3) * 64;
    int tid = threadIdx.x;
    for (int i = 0; i < 16; ++i) {
        int e = i * 256 + tid;
        int c = e >> 6, nn = e & 63;
        t[c][nn] = x[((size_t)b * C_ + c) * N_ + n0 + nn];
    }
    __syncthreads();
    for (int i = 0; i < 16; ++i) {
        int e = i * 256 + tid;
        int nn = e >> 6, c = e & 63;
        xT[((size_t)b * N_ + n0 + nn) * C_ + c] = t[c][nn];
    }
    int q = tid >> 6, L = tid & 63;
    int mloc = q * 16 + (L & 15);
    int k8 = (L >> 4) * 8;
    size_t cb = (size_t)(b * 256 + (n0 >> 4) + q) * 2 * 512;   // ushort units
#pragma unroll
    for (int h = 0; h < 2; ++h) {
        short8 hi;
#pragma unroll
        for (int j = 0; j < 8; ++j)
            hi[j] = (short)f2bf(t[h * 32 + k8 + j][mloc]);
        *(short8*)(xfrag + cb + h * 512 + L * 8) = hi;
    }
    if (tid < 64) {
        float s = 0.f;
        for (int c = 0; c < C_; ++c) { float v = t[c][tid]; s += v * v; }
        x2[(size_t)b * N_ + n0 + tid] = s;
    }
}

// append packed (20-bit sortable key | 12-bit index)
#define APPEND(KEY, TAU, LN, MIDX)                                      \
    if ((KEY) > (TAU)) {                                                \
        unsigned u = __float_as_uint(KEY);                              \
        u = (u & 0x80000000u) ? ~u : (u | 0x80000000u);                 \
        unsigned pk = (u & 0xFFFFF000u) | (unsigned)(MIDX);             \
        int sl = atomicAdd(&cnt_s[LN], 1);                              \
        if (sl < CAP) buf_s[LN][sl] = pk;                               \
    }

// MFMA scan (bf16-hi) + threshold compaction + in-LDS per-half top-12.
__global__ __launch_bounds__(256, 4) void k_topk_mf(const unsigned short* __restrict__ xfrag,
                                                    const float* __restrict__ x2,
                                                    unsigned* __restrict__ cand24,
                                                    int* __restrict__ cnt2) {
    __shared__ int cnt_s[64];
    __shared__ unsigned buf_s[64][CAP];
    int b    = blockIdx.x & 7;
    int mh   = (blockIdx.x >> 3) & 1;
    int ng   = blockIdx.x >> 4;                  // 0..63
    int wave = threadIdx.x >> 6, lane = threadIdx.x & 63;
    if (threadIdx.x < 64) cnt_s[threadIdx.x] = 0;

    const short8* fr = (const short8*)xfrag;     // 16B units; chunk = 64 short8

    short8 Bh[4][2];
#pragma unroll
    for (int q = 0; q < 4; ++q)
#pragma unroll
        for (int h = 0; h < 2; ++h) {
            int ch = ((b * 256 + ng * 4 + q) * 2 + h);
            Bh[q][h] = fr[(size_t)ch * 64 + lane];
        }

    float tau[4];
#pragma unroll
    for (int q = 0; q < 4; ++q) {
        float x2n = x2[b * N_ + ng * 64 + q * 16 + (lane & 15)];
        tau[q] = TAU_A * sqrtf(fmaf(4.f, x2n, 128.f)) - 64.f;
    }

    int mt0 = mh * 128 + wave * 32;              // m-tile start (32 tiles per wave)
    const short8* pA = fr + (size_t)(b * 256 + mt0) * 2 * 64 + lane;
    const f32x4*  px2 = (const f32x4*)(x2 + b * N_ + mt0 * 16 + (lane >> 4) * 4);
    short8 Ah0 = pA[0], Ah1 = pA[64];
    f32x4 x2v = *px2;

    __syncthreads();   // cnt_s zeroed

    for (int i = 0; i < 32; ++i) {
        if (i != 31) { pA += 128; px2 += 4; }
        short8 nAh0 = pA[0], nAh1 = pA[64];
        f32x4 nx2 = *px2;

        int mbase = (mt0 + i) * 16 + (lane >> 4) * 4;

#pragma unroll
        for (int q = 0; q < 4; ++q) {
            f32x4 acc = {0.f, 0.f, 0.f, 0.f};
            acc = __builtin_amdgcn_mfma_f32_16x16x32_bf16(Ah0, Bh[q][0], acc, 0, 0, 0);
            acc = __builtin_amdgcn_mfma_f32_16x16x32_bf16(Ah1, Bh[q][1], acc, 0, 0, 0);
            float k0 = fmaf(2.f, acc[0], -x2v[0]);
            float k1 = fmaf(2.f, acc[1], -x2v[1]);
            float k2 = fmaf(2.f, acc[2], -x2v[2]);
            float k3 = fmaf(2.f, acc[3], -x2v[3]);
            int ln = q * 16 + (lane & 15);
            APPEND(k0, tau[q], ln, mbase + 0)
            APPEND(k1, tau[q], ln, mbase + 1)
            APPEND(k2, tau[q], ln, mbase + 2)
            APPEND(k3, tau[q], ln, mbase + 3)
        }
        Ah0 = nAh0; Ah1 = nAh1; x2v = nx2;
    }

    __syncthreads();
    if (threadIdx.x < 64) {
        int r = threadIdx.x;
        int c = cnt_s[r];
        size_t grow = (size_t)b * N_ + ng * 64 + r;
        cnt2[grow * 2 + mh] = c;
        int cc = min(c, CAP);
        unsigned best[12];
#pragma unroll
        for (int j = 0; j < 12; ++j) best[j] = 0u;
        for (int s = 0; s < cc; ++s) {
            unsigned v = buf_s[r][s];
            if (v > best[0]) {
                best[0] = v;
#pragma unroll
                for (int j = 0; j < 11; ++j) {
                    bool sw = best[j] > best[j + 1];
                    unsigned t = best[j];
                    best[j]     = sw ? best[j + 1] : best[j];
                    best[j + 1] = sw ? t : best[j + 1];
                }
            }
        }
#pragma unroll
        for (int j = 0; j < 12; ++j)
            cand24[grow * 24 + mh * 12 + j] = best[11 - j];
    }
}

// exact fp64 re-rank of up to 24 coarse candidates -> true top-9.
__global__ void k_refine(const float* __restrict__ xT, const unsigned* __restrict__ cand24,
                         const int* __restrict__ cnt2, int* __restrict__ idx9) {
    int wave = threadIdx.x >> 6, lane = threadIdx.x & 63;
    int half = lane >> 5, hl = lane & 31;
    int b = blockIdx.x & 7;
    int row = b * N_ + (blockIdx.x >> 3) * 8 + wave * 2 + half;
    int c0 = cnt2[(size_t)row * 2 + 0];
    int c1 = cnt2[(size_t)row * 2 + 1];
    bool ok = (c0 + c1 >= KNN) && (c0 <= CAP) && (c1 <= CAP);
    int c0c = min(c0, 12), c1c = min(c1, 12);

    double mykey = -1e300; int myidx = 0x7fffffff;
    bool valid = ok && ((hl < 12) ? (hl < c0c) : (hl < 24 && (hl - 12) < c1c));
    if (valid) {
        int m = (int)(cand24[(size_t)row * 24 + hl] & 0xFFFu);
        const float* xi = xT + (size_t)row * C_;
        const float* xm = xT + (((size_t)b << 12) + m) * C_;
        double d = 0.0, s2 = 0.0;
#pragma unroll
        for (int c4 = 0; c4 < 16; ++c4) {
            float4 a = *(const float4*)(xi + c4 * 4);
            float4 v = *(const float4*)(xm + c4 * 4);
            d = fma((double)a.x, (double)v.x, d);  s2 = fma((double)v.x, (double)v.x, s2);
            d = fma((double)a.y, (double)v.y, d);  s2 = fma((double)v.y, (double)v.y, s2);
            d = fma((double)a.z, (double)v.z, d);  s2 = fma((double)v.z, (double)v.z, s2);
            d = fma((double)a.w, (double)v.w, d);  s2 = fma((double)v.w, (double)v.w, s2);
        }
        mykey = 2.0 * d - s2;
        myidx = m;
    }
    for (int r = 0; r < KNN; ++r) {
        double k = mykey; int ix = myidx;
#pragma unroll
        for (int o = 16; o; o >>= 1) {
            double ok2 = __shfl_xor(k, o); int oi = __shfl_xor(ix, o);
            bool take = (ok2 > k) || (ok2 == k && oi < ix);
            k = take ? ok2 : k; ix = take ? oi : ix;
        }
        if (ok && hl == 0) idx9[(size_t)row * KNN + r] = ix;
        if (myidx == ix) { mykey = -1e300; myidx = 0x7fffffff; }
    }
}

// exact fp64 full scan for rows where the threshold buffers failed (insurance).
__global__ void k_fallback(const float* __restrict__ xT, const int* __restrict__ cnt2,
                           int* __restrict__ idx9) {
    int wave = threadIdx.x >> 6, lane = threadIdx.x & 63;
    int row = blockIdx.x * 4 + wave;
    int c0 = cnt2[(size_t)row * 2 + 0];
    int c1 = cnt2[(size_t)row * 2 + 1];
    if ((c0 + c1 >= KNN) && (c0 <= CAP) && (c1 <= CAP)) return;
    int b = row >> 12;
    const float* xi = xT + (size_t)row * C_;
    float4 xr[16];
#pragma unroll
    for (int c4 = 0; c4 < 16; ++c4) xr[c4] = *(const float4*)(xi + c4 * 4);
    double sk[9]; int si[9];
#pragma unroll
    for (int j = 0; j < 9; ++j) { sk[j] = -1e300; si[j] = 0x7fffffff; }
    for (int mb = 0; mb < N_; mb += 64) {
        int m = mb + lane;
        const float* xm = xT + (((size_t)b << 12) + m) * C_;
        double d0 = 0.0, d1 = 0.0, s0 = 0.0, s1 = 0.0;
#pragma unroll
        for (int c4 = 0; c4 < 16; c4 += 2) {
            float4 v = *(const float4*)(xm + c4 * 4);
            float4 w = *(const float4*)(xm + c4 * 4 + 4);
            float4 a = xr[c4], bb = xr[c4 + 1];
            d0 = fma((double)a.x, (double)v.x, d0);  s0 = fma((double)v.x, (double)v.x, s0);
            d0 = fma((double)a.y, (double)v.y, d0);  s0 = fma((double)v.y, (double)v.y, s0);
            d0 = fma((double)a.z, (double)v.z, d0);  s0 = fma((double)v.z, (double)v.z, s0);
            d0 = fma((double)a.w, (double)v.w, d0);  s0 = fma((double)v.w, (double)v.w, s0);
            d1 = fma((double)bb.x, (double)w.x, d1); s1 = fma((double)w.x, (double)w.x, s1);
            d1 = fma((double)bb.y, (double)w.y, d1); s1 = fma((double)w.y, (double)w.y, s1);
            d1 = fma((double)bb.z, (double)w.z, d1); s1 = fma((double)w.z, (double)w.z, s1);
            d1 = fma((double)bb.w, (double)w.w, d1); s1 = fma((double)w.w, (double)w.w, s1);
        }
        double key = 2.0 * (d0 + d1) - (s0 + s1);
        if (key > sk[0] || (key == sk[0] && m < si[0])) {
            sk[0] = key; si[0] = m;
#pragma unroll
            for (int j = 0; j < 8; ++j) {
                bool sw = (sk[j] > sk[j + 1]) || (sk[j] == sk[j + 1] && si[j] < si[j + 1]);
                double tk = sk[j]; int ti = si[j];
                sk[j]     = sw ? sk[j + 1] : sk[j];
                si[j]     = sw ? si[j + 1] : si[j];
                sk[j + 1] = sw ? tk : sk[j + 1];
                si[j + 1] = sw ? ti : si[j + 1];
            }
        }
    }
    for (int r = 0; r < KNN; ++r) {
        double k = sk[8]; int ix = si[8];
#pragma unroll
        for (int o = 32; o; o >>= 1) {
            double ok = __shfl_xor(k, o); int oi = __shfl_xor(ix, o);
            bool take = (ok > k) || (ok == k && oi < ix);
            k = take ? ok : k; ix = take ? oi : ix;
        }
        if (lane == 0) idx9[(size_t)row * KNN + r] = ix;
        if (si[8] == ix) {
#pragma unroll
            for (int j = 8; j > 0; --j) { sk[j] = sk[j - 1]; si[j] = si[j - 1]; }
            sk[0] = -1e300; si[0] = 0x7fffffff;
        }
    }
}

// fused gather-max + MFMA 1x1 conv + bias + ReLU.
// block: 4 waves, 64 n. h LDS [128c][65n]. Wave owns 32 out-channels (2 o-tiles).
__global__ __launch_bounds__(256, 2) void k_gemm(const float* __restrict__ xT,
                                                 const int* __restrict__ idx9,
                                                 const unsigned short* __restrict__ wfrag,
                                                 const float* __restrict__ bias,
                                                 float* __restrict__ out) {
    __shared__ float h[128][65];
    int b  = blockIdx.x & 7;                     // XCD-pinned batch
    int n0 = (blockIdx.x >> 3) * 64;
    int wave = threadIdx.x >> 6, lane = threadIdx.x & 63;

    // W A-fragments: 2 o-tiles x 4 k-chunks x hi/lo (64 VGPR)
    const short8* fw = (const short8*)wfrag;
    short8 Wh[2][4], Wl[2][4];
#pragma unroll
    for (int t = 0; t < 2; ++t)
#pragma unroll
        for (int kc = 0; kc < 4; ++kc) {
            size_t cb = (size_t)((wave * 2 + t) * 4 + kc) * 2 * 64;
            Wh[t][kc] = fw[cb + lane];
            Wl[t][kc] = fw[cb + 64 + lane];
        }

    // gather-max into h (c-major): lane = channel
    for (int r = 0; r < 16; ++r) {
        int nn = wave * 16 + r;
        size_t row = (size_t)b * N_ + n0 + nn;
        const int* id = idx9 + row * KNN;
        float m = -FLT_MAX;
#pragma unroll
        for (int k = 0; k < KNN; ++k) {
            int j = id[k];
            m = fmaxf(m, xT[(((size_t)b << 12) + j) * C_ + lane]);
        }
        float xic = xT[row * C_ + lane];
        h[lane][nn]      = xic;
        h[64 + lane][nn] = m - xic;
    }
    __syncthreads();

    // MFMA: per wave 2 o-tiles x 4 n-tiles, K = 128 over 4 chunks
    f32x4 acc[2][4];
#pragma unroll
    for (int t = 0; t < 2; ++t)
#pragma unroll
        for (int nt = 0; nt < 4; ++nt) acc[t][nt] = (f32x4){0.f, 0.f, 0.f, 0.f};

    int cb0 = (lane >> 4) * 8;
    int nl  = lane & 15;
#pragma unroll
    for (int kc = 0; kc < 4; ++kc) {
#pragma unroll
        for (int nt = 0; nt < 4; ++nt) {
            short8 bh, bl;
#pragma unroll
            for (int j = 0; j < 8; ++j) {
                float v = h[kc * 32 + cb0 + j][nt * 16 + nl];
                unsigned short hb = f2bf(v);
                bl[j] = (short)f2bf(v - bf2f(hb));
                bh[j] = (short)hb;
            }
#pragma unroll
            for (int t = 0; t < 2; ++t) {
                acc[t][nt] = __builtin_amdgcn_mfma_f32_16x16x32_bf16(Wh[t][kc], bh, acc[t][nt], 0, 0, 0);
                acc[t][nt] = __builtin_amdgcn_mfma_f32_16x16x32_bf16(Wl[t][kc], bh, acc[t][nt], 0, 0, 0);
                acc[t][nt] = __builtin_amdgcn_mfma_f32_16x16x32_bf16(Wh[t][kc], bl, acc[t][nt], 0, 0, 0);
            }
        }
    }
    __syncthreads();   // h reads done; reuse h for output staging

    // epilogue: bias + ReLU, stage [o][n] in h
    f32x4 bs[2];
#pragma unroll
    for (int t = 0; t < 2; ++t)
        bs[t] = *(const f32x4*)(bias + wave * 32 + t * 16 + (lane >> 4) * 4);
#pragma unroll
    for (int t = 0; t < 2; ++t)
#pragma unroll
        for (int nt = 0; nt < 4; ++nt)
#pragma unroll
            for (int j = 0; j < 4; ++j) {
                float v = acc[t][nt][j] + bs[t][j];
                h[wave * 32 + t * 16 + (lane >> 4) * 4 + j][nt * 16 + nl] = fmaxf(v, 0.f);
            }
    __syncthreads();

    // coalesced output: each wave writes its 32 o-rows
#pragma unroll
    for (int rr = 0; rr < 32; ++rr) {
        int o = wave * 32 + rr;
        out[((size_t)b * OUT_ + o) * N_ + n0 + lane] = h[o][lane];
    }
}

extern "C" void kernel_launch(void* const* d_in, const int* in_sizes, int n_in,
                              void* d_out, int out_size, void* d_ws, size_t ws_size,
                              hipStream_t stream) {
    const float* x    = (const float*)d_in[0];
    const float* W    = (const float*)d_in[1];
    const float* bias = (const float*)d_in[2];
    float* out = (float*)d_out;
    char* ws = (char*)d_ws;

    float*          xT     = (float*)(ws);
    unsigned short* xfrag  = (unsigned short*)(ws + 8388608);
    int*            idx9   = (int*)(ws + 8388608);        // aliases xfrag (dead by refine)
    float*          x2     = (float*)(ws + 16777216);
    unsigned short* wfrag  = (unsigned short*)(ws + 16908288);
    unsigned*       cand24 = (unsigned*)(ws + 16973824);
    int*            cnt2   = (int*)(ws + 20119552);

    k_wt       <<<dim3(8),    dim3(256), 0, stream>>>(W, wfrag);
    k_transpose<<<dim3(512),  dim3(256), 0, stream>>>(x, xT, x2, xfrag);
    k_topk_mf  <<<dim3(1024), dim3(256), 0, stream>>>(xfrag, x2, cand24, cnt2);
    k_refine   <<<dim3(4096), dim3(256), 0, stream>>>(xT, cand24, cnt2, idx9);
    k_fallback <<<dim3(8192), dim3(256), 0, stream>>>(xT, cnt2, idx9);
    k_gemm     <<<dim3(512),  dim3(256), 0, stream>>>(xT, idx9, wfrag, bias, out);
}